// Round 1
// baseline (2738.019 us; speedup 1.0000x reference)
//
#include <hip/hip_runtime.h>
#include <math.h>

// Problem constants (fixed by reference)
static constexpr int NNODE = 4096;
static constexpr int HDIM  = 256;
static constexpr int DIN   = 128;
static constexpr int HEADS = 8;
static constexpr int DH    = 32;

// ---------------------------------------------------------------------------
// degree count: deg[dst] += 1 per edge
__global__ void k_deg(const int* __restrict__ ei, float* __restrict__ deg, int E) {
    int e = blockIdx.x * 256 + threadIdx.x;
    if (e < E) atomicAdd(&deg[ei[E + e]], 1.0f);
}

// dinv = rsqrt(deg+1), invdeg = 1/(deg+1)
__global__ void k_norm(const float* __restrict__ deg, float* __restrict__ dinv,
                       float* __restrict__ invdeg) {
    int n = blockIdx.x * 256 + threadIdx.x;
    if (n < NNODE) {
        float d = deg[n] + 1.0f;
        dinv[n]   = rsqrtf(d);
        invdeg[n] = 1.0f / d;
    }
}

// ---------------------------------------------------------------------------
// fp32 tiled GEMM: C[M=4096, Nout] = act(A) @ B (+bias) (+addsrc)
// TB=0: B is [K, Nout] row-major. TB=1: B is [Nout, K] (torch W, y = x@W.T)
template<int K, bool TB, bool RELUA, bool BIAS, bool ADD>
__global__ __launch_bounds__(256) void k_gemm(const float* __restrict__ A,
                                              const float* __restrict__ B,
                                              const float* __restrict__ bias,
                                              const float* __restrict__ addsrc,
                                              float* __restrict__ C, int Nout) {
    __shared__ float As[16][68];   // padded: 68*4=272B row stride, 16B aligned
    __shared__ float Bs[16][64];
    const int tid = threadIdx.x;
    const int m0 = blockIdx.y * 64;
    const int n0 = blockIdx.x * 64;
    const int tx = tid & 15;
    const int ty = tid >> 4;
    const int ar = tid >> 2;   // 0..63
    const int aq = tid & 3;    // 0..3
    float acc[4][4] = {};

    for (int k0 = 0; k0 < K; k0 += 16) {
        __syncthreads();
        {   // A tile 64x16
            float4 v = *(const float4*)&A[(size_t)(m0 + ar) * K + k0 + aq * 4];
            if (RELUA) {
                v.x = fmaxf(v.x, 0.f); v.y = fmaxf(v.y, 0.f);
                v.z = fmaxf(v.z, 0.f); v.w = fmaxf(v.w, 0.f);
            }
            As[aq*4+0][ar] = v.x; As[aq*4+1][ar] = v.y;
            As[aq*4+2][ar] = v.z; As[aq*4+3][ar] = v.w;
        }
        if (!TB) {  // B tile 16x64, row-major [K,Nout]
            int kk = tid >> 4, jq = tid & 15;
            float4 v = *(const float4*)&B[(size_t)(k0 + kk) * Nout + n0 + jq * 4];
            *(float4*)&Bs[kk][jq * 4] = v;
        } else {    // B [Nout,K]: Bs[k][j] = B[(n0+j)*K + k0+k]
            float4 v = *(const float4*)&B[(size_t)(n0 + ar) * K + k0 + aq * 4];
            Bs[aq*4+0][ar] = v.x; Bs[aq*4+1][ar] = v.y;
            Bs[aq*4+2][ar] = v.z; Bs[aq*4+3][ar] = v.w;
        }
        __syncthreads();
        #pragma unroll
        for (int kk = 0; kk < 16; ++kk) {
            float4 a = *(const float4*)&As[kk][ty * 4];
            float4 b = *(const float4*)&Bs[kk][tx * 4];
            float av[4] = {a.x, a.y, a.z, a.w};
            float bv[4] = {b.x, b.y, b.z, b.w};
            #pragma unroll
            for (int i = 0; i < 4; ++i)
                #pragma unroll
                for (int j = 0; j < 4; ++j)
                    acc[i][j] += av[i] * bv[j];
        }
    }
    #pragma unroll
    for (int i = 0; i < 4; ++i) {
        int row = m0 + ty * 4 + i;
        #pragma unroll
        for (int j = 0; j < 4; ++j) {
            int col = n0 + tx * 4 + j;
            float v = acc[i][j];
            if (BIAS) v += bias[col];
            size_t idx = (size_t)row * Nout + col;
            if (ADD) v += addsrc[idx];
            C[idx] = v;
        }
    }
}

// ---------------------------------------------------------------------------
// agg init: self-loop term + bias: agg[n,c] = hW[n,c]*invdeg[n] + b[c]
__global__ void k_init_agg(const float* __restrict__ hW, const float* __restrict__ invdeg,
                           const float* __restrict__ b, float* __restrict__ agg) {
    int idx = blockIdx.x * 256 + threadIdx.x;
    int n = idx >> 8, c = idx & 255;
    agg[idx] = hW[idx] * invdeg[n] + b[c];
}

// scatter: agg[dst,c] += hW[src,c] * dinv[src]*dinv[dst]; one wave per edge
__global__ __launch_bounds__(256) void k_scatter(const float* __restrict__ hW,
                                                 const int* __restrict__ ei,
                                                 const float* __restrict__ dinv,
                                                 float* __restrict__ agg, int E) {
    long long idx = (long long)blockIdx.x * 256 + threadIdx.x;
    if (idx >= (long long)E * 64) return;
    int e = (int)(idx >> 6);
    int c = (int)(idx & 63) * 4;
    int s = ei[e], d = ei[E + e];
    float nrm = dinv[s] * dinv[d];
    float4 hv = *(const float4*)&hW[(size_t)s * HDIM + c];
    float* ap = &agg[(size_t)d * HDIM + c];
    atomicAdd(ap + 0, hv.x * nrm);
    atomicAdd(ap + 1, hv.y * nrm);
    atomicAdd(ap + 2, hv.z * nrm);
    atomicAdd(ap + 3, hv.w * nrm);
}

// ---------------------------------------------------------------------------
// flash attention fp32: one q-row per thread, online softmax entirely in regs
__global__ __launch_bounds__(128) void k_attn(const float* __restrict__ qkv,
                                              float* __restrict__ o) {
    const int hd  = blockIdx.x;                       // head
    const int row = blockIdx.y * 128 + threadIdx.x;   // q row
    const int tid = threadIdx.x;
    __shared__ float Kl[32 * 32];
    __shared__ float Vl[32 * 32];
    const float scale = 0.17677669529663687f;  // 1/sqrt(32)
    float q[32];
    {
        const float* qp = qkv + (size_t)row * 768 + hd * DH;
        #pragma unroll
        for (int w = 0; w < 8; ++w) {
            float4 v = *(const float4*)&qp[w * 4];
            q[w*4+0] = v.x * scale; q[w*4+1] = v.y * scale;
            q[w*4+2] = v.z * scale; q[w*4+3] = v.w * scale;
        }
    }
    float oa[32] = {};
    float m = -INFINITY, l = 0.f;

    for (int t = 0; t < NNODE / 32; ++t) {
        __syncthreads();
        #pragma unroll
        for (int f = tid; f < 256; f += 128) {   // 32x32 K and V tiles
            int j = f >> 3, w = f & 7;
            size_t base = (size_t)(t * 32 + j) * 768 + hd * DH + w * 4;
            *(float4*)&Kl[j * 32 + w * 4] = *(const float4*)&qkv[base + 256];
            *(float4*)&Vl[j * 32 + w * 4] = *(const float4*)&qkv[base + 512];
        }
        __syncthreads();
        float sv[32];
        float smax = -INFINITY;
        #pragma unroll
        for (int j = 0; j < 32; ++j) {
            float acc = 0.f;
            #pragma unroll
            for (int w = 0; w < 8; ++w) {
                float4 kv = *(const float4*)&Kl[j * 32 + w * 4];
                acc += q[w*4+0]*kv.x + q[w*4+1]*kv.y + q[w*4+2]*kv.z + q[w*4+3]*kv.w;
            }
            sv[j] = acc;
            smax = fmaxf(smax, acc);
        }
        float mnew = fmaxf(m, smax);
        float corr = __expf(m - mnew);   // first tile: exp(-inf)=0, oa already 0
        l *= corr;
        #pragma unroll
        for (int d = 0; d < 32; ++d) oa[d] *= corr;
        #pragma unroll
        for (int j = 0; j < 32; ++j) {
            float p = __expf(sv[j] - mnew);
            l += p;
            #pragma unroll
            for (int w = 0; w < 8; ++w) {
                float4 vv = *(const float4*)&Vl[j * 32 + w * 4];
                oa[w*4+0] += p*vv.x; oa[w*4+1] += p*vv.y;
                oa[w*4+2] += p*vv.z; oa[w*4+3] += p*vv.w;
            }
        }
        m = mnew;
    }
    float inv = 1.f / l;
    float* op = o + (size_t)row * HDIM + hd * DH;
    #pragma unroll
    for (int w = 0; w < 8; ++w) {
        float4 v = {oa[w*4+0]*inv, oa[w*4+1]*inv, oa[w*4+2]*inv, oa[w*4+3]*inv};
        *(float4*)&op[w * 4] = v;
    }
}

// ---------------------------------------------------------------------------
// fused MLP heads: one node per block; 256 threads compute both 128-d hiddens
__global__ __launch_bounds__(256) void k_heads(const float* __restrict__ h,
        const float* __restrict__ fp1w, const float* __restrict__ fp1b,
        const float* __restrict__ fp2w, const float* __restrict__ fp2b,
        const float* __restrict__ pd1w, const float* __restrict__ pd1b,
        const float* __restrict__ pd2w, const float* __restrict__ pd2b,
        float* __restrict__ out) {
    int n = blockIdx.x;
    int tid = threadIdx.x;
    __shared__ float hrow[256];
    __shared__ float t[256];
    __shared__ float logits[16];
    hrow[tid] = h[(size_t)n * HDIM + tid];
    __syncthreads();
    {
        int i = tid & 127;
        const float* wrow = (tid < 128) ? (fp1w + (size_t)i * 256) : (pd1w + (size_t)i * 256);
        float acc = 0.f;
        #pragma unroll 8
        for (int k = 0; k < 256; k += 4) {
            float4 wv = *(const float4*)&wrow[k];
            acc += hrow[k]*wv.x + hrow[k+1]*wv.y + hrow[k+2]*wv.z + hrow[k+3]*wv.w;
        }
        acc += (tid < 128) ? fp1b[i] : pd1b[i];
        t[tid] = fmaxf(acc, 0.f);
    }
    __syncthreads();
    if (tid < 13) {
        const float* wrow; const float* tt; float bb;
        if (tid < 3) { wrow = fp2w + tid * 128;      tt = t;       bb = fp2b[tid]; }
        else         { wrow = pd2w + (tid-3) * 128;  tt = t + 128; bb = pd2b[tid-3]; }
        float acc = bb;
        #pragma unroll 8
        for (int k = 0; k < 128; k += 4) {
            float4 wv = *(const float4*)&wrow[k];
            acc += tt[k]*wv.x + tt[k+1]*wv.y + tt[k+2]*wv.z + tt[k+3]*wv.w;
        }
        logits[tid] = acc;
    }
    __syncthreads();
    if (tid < 3) {
        float mx = fmaxf(logits[0], fmaxf(logits[1], logits[2]));
        float e0 = __expf(logits[0]-mx), e1 = __expf(logits[1]-mx), e2 = __expf(logits[2]-mx);
        float mine = (tid == 0) ? e0 : ((tid == 1) ? e1 : e2);
        out[(size_t)n * 3 + tid] = mine / (e0 + e1 + e2);
    } else if (tid < 13) {
        out[(size_t)NNODE * 3 + (size_t)n * 10 + (tid - 3)] =
            1.0f / (1.0f + __expf(-logits[tid]));
    }
}

// ---------------------------------------------------------------------------
extern "C" void kernel_launch(void* const* d_in, const int* in_sizes, int n_in,
                              void* d_out, int out_size, void* d_ws, size_t ws_size,
                              hipStream_t stream) {
    const float* x    = (const float*)d_in[0];
    const int*   ei   = (const int*)  d_in[1];
    const float* W1   = (const float*)d_in[2];
    const float* b1   = (const float*)d_in[3];
    const float* W2   = (const float*)d_in[4];
    const float* b2   = (const float*)d_in[5];
    const float* W3   = (const float*)d_in[6];
    const float* b3   = (const float*)d_in[7];
    const float* in_w = (const float*)d_in[8];
    const float* in_b = (const float*)d_in[9];
    const float* outw = (const float*)d_in[10];
    const float* outb = (const float*)d_in[11];
    const float* fp1w = (const float*)d_in[12];
    const float* fp1b = (const float*)d_in[13];
    const float* fp2w = (const float*)d_in[14];
    const float* fp2b = (const float*)d_in[15];
    const float* pd1w = (const float*)d_in[16];
    const float* pd1b = (const float*)d_in[17];
    const float* pd2w = (const float*)d_in[18];
    const float* pd2b = (const float*)d_in[19];
    float* out = (float*)d_out;

    const int E = in_sizes[1] / 2;

    float* ws     = (float*)d_ws;
    float* deg    = ws;
    float* dinv   = ws + 4096;
    float* invdeg = ws + 8192;
    float* bufA   = ws + 12288;                 // 4096*256
    float* bufB   = bufA + NNODE * HDIM;
    float* bufC   = bufB + NNODE * HDIM;
    float* qkvb   = bufC + NNODE * HDIM;        // 4096*768

    // degree / norm (shared by all 3 convs)
    hipMemsetAsync(deg, 0, NNODE * sizeof(float), stream);
    k_deg<<<(E + 255) / 256, 256, 0, stream>>>(ei, deg, E);
    k_norm<<<NNODE / 256, 256, 0, stream>>>(deg, dinv, invdeg);

    const int scat_grid = (int)(((long long)E * 64 + 255) / 256);
    dim3 g256(HDIM / 64, NNODE / 64);   // (4,64)
    dim3 g768(768 / 64, NNODE / 64);    // (12,64)

    // conv1: hW = x@W1 ; agg = hW*invdeg + b1 ; scatter
    k_gemm<DIN, false, false, false, false><<<g256, 256, 0, stream>>>(x, W1, nullptr, nullptr, bufA, HDIM);
    k_init_agg<<<NNODE, 256, 0, stream>>>(bufA, invdeg, b1, bufB);
    k_scatter<<<scat_grid, 256, 0, stream>>>(bufA, ei, dinv, bufB, E);

    // conv2 (relu of agg1 folded into A-load)
    k_gemm<HDIM, false, true, false, false><<<g256, 256, 0, stream>>>(bufB, W2, nullptr, nullptr, bufA, HDIM);
    k_init_agg<<<NNODE, 256, 0, stream>>>(bufA, invdeg, b2, bufC);
    k_scatter<<<scat_grid, 256, 0, stream>>>(bufA, ei, dinv, bufC, E);

    // conv3
    k_gemm<HDIM, false, true, false, false><<<g256, 256, 0, stream>>>(bufC, W3, nullptr, nullptr, bufA, HDIM);
    k_init_agg<<<NNODE, 256, 0, stream>>>(bufA, invdeg, b3, bufB);
    k_scatter<<<scat_grid, 256, 0, stream>>>(bufA, ei, dinv, bufB, E);
    // h = bufB (no relu)

    // MHA
    k_gemm<HDIM, true, false, true, false><<<g768, 256, 0, stream>>>(bufB, in_w, in_b, nullptr, qkvb, 768);
    k_attn<<<dim3(HEADS, NNODE / 128), 128, 0, stream>>>(qkvb, bufA);
    // h_final = h + o@out_w.T + out_b
    k_gemm<HDIM, true, false, true, true><<<g256, 256, 0, stream>>>(bufA, outw, outb, bufB, bufC, HDIM);

    // MLP heads -> d_out
    k_heads<<<NNODE, 256, 0, stream>>>(bufC, fp1w, fp1b, fp2w, fp2b,
                                       pd1w, pd1b, pd2w, pd2b, out);
}

// Round 2
// 745.485 us; speedup vs baseline: 3.6728x; 3.6728x over previous
//
#include <hip/hip_runtime.h>
#include <math.h>

static constexpr int NNODE = 4096;
static constexpr int HDIM  = 256;
static constexpr int DIN   = 128;
static constexpr int HEADS = 8;
static constexpr int DH    = 32;
static constexpr int SPLIT = 4;     // attention K-split
static constexpr int KCH   = NNODE / SPLIT;

// ---------------------------------------------------------------------------
__global__ void k_deg(const int* __restrict__ ei, int* __restrict__ degi, int E) {
    int e = blockIdx.x * 256 + threadIdx.x;
    if (e < E) atomicAdd(&degi[ei[E + e]], 1);
}

// one block: exclusive scan of degi -> off/cursor, plus dinv/invdeg
__global__ __launch_bounds__(256) void k_scan_norm(const int* __restrict__ degi,
        int* __restrict__ off, int* __restrict__ cursor,
        float* __restrict__ dinv, float* __restrict__ invdeg) {
    __shared__ int partial[256];
    __shared__ int basesh[256];
    int t = threadIdx.x;
    int local[16];
    int s = 0;
    #pragma unroll
    for (int i = 0; i < 16; ++i) { local[i] = degi[t * 16 + i]; s += local[i]; }
    partial[t] = s;
    __syncthreads();
    if (t == 0) {
        int run = 0;
        for (int i = 0; i < 256; ++i) { basesh[i] = run; run += partial[i]; }
    }
    __syncthreads();
    int b = basesh[t];
    #pragma unroll
    for (int i = 0; i < 16; ++i) {
        int n = t * 16 + i;
        off[n] = b; cursor[n] = b; b += local[i];
        float d = (float)local[i] + 1.0f;
        dinv[n]   = rsqrtf(d);
        invdeg[n] = 1.0f / d;
    }
}

__global__ void k_fill(const int* __restrict__ ei, int* __restrict__ cursor,
                       int* __restrict__ csr, int E) {
    int e = blockIdx.x * 256 + threadIdx.x;
    if (e < E) {
        int d = ei[E + e];
        int p = atomicAdd(&cursor[d], 1);
        csr[p] = ei[e];
    }
}

// ---------------------------------------------------------------------------
// fp32 tiled GEMM: C[M=4096, Nout] = act(A) @ B (+bias) (+addsrc)
template<int K, bool TB, bool RELUA, bool BIAS, bool ADD>
__global__ __launch_bounds__(256) void k_gemm(const float* __restrict__ A,
                                              const float* __restrict__ B,
                                              const float* __restrict__ bias,
                                              const float* __restrict__ addsrc,
                                              float* __restrict__ C, int Nout) {
    __shared__ float As[16][68];
    __shared__ float Bs[16][64];
    const int tid = threadIdx.x;
    const int m0 = blockIdx.y * 64;
    const int n0 = blockIdx.x * 64;
    const int tx = tid & 15;
    const int ty = tid >> 4;
    const int ar = tid >> 2;
    const int aq = tid & 3;
    float acc[4][4] = {};

    for (int k0 = 0; k0 < K; k0 += 16) {
        __syncthreads();
        {
            float4 v = *(const float4*)&A[(size_t)(m0 + ar) * K + k0 + aq * 4];
            if (RELUA) {
                v.x = fmaxf(v.x, 0.f); v.y = fmaxf(v.y, 0.f);
                v.z = fmaxf(v.z, 0.f); v.w = fmaxf(v.w, 0.f);
            }
            As[aq*4+0][ar] = v.x; As[aq*4+1][ar] = v.y;
            As[aq*4+2][ar] = v.z; As[aq*4+3][ar] = v.w;
        }
        if (!TB) {
            int kk = tid >> 4, jq = tid & 15;
            float4 v = *(const float4*)&B[(size_t)(k0 + kk) * Nout + n0 + jq * 4];
            *(float4*)&Bs[kk][jq * 4] = v;
        } else {
            float4 v = *(const float4*)&B[(size_t)(n0 + ar) * K + k0 + aq * 4];
            Bs[aq*4+0][ar] = v.x; Bs[aq*4+1][ar] = v.y;
            Bs[aq*4+2][ar] = v.z; Bs[aq*4+3][ar] = v.w;
        }
        __syncthreads();
        #pragma unroll
        for (int kk = 0; kk < 16; ++kk) {
            float4 a = *(const float4*)&As[kk][ty * 4];
            float4 b = *(const float4*)&Bs[kk][tx * 4];
            float av[4] = {a.x, a.y, a.z, a.w};
            float bv[4] = {b.x, b.y, b.z, b.w};
            #pragma unroll
            for (int i = 0; i < 4; ++i)
                #pragma unroll
                for (int j = 0; j < 4; ++j)
                    acc[i][j] += av[i] * bv[j];
        }
    }
    #pragma unroll
    for (int i = 0; i < 4; ++i) {
        int row = m0 + ty * 4 + i;
        #pragma unroll
        for (int j = 0; j < 4; ++j) {
            int col = n0 + tx * 4 + j;
            float v = acc[i][j];
            if (BIAS) v += bias[col];
            size_t idx = (size_t)row * Nout + col;
            if (ADD) v += addsrc[idx];
            C[idx] = v;
        }
    }
}

// ---------------------------------------------------------------------------
// CSR gather: agg[n,c] = dinv[n]*sum_{s in adj(n)} hW[s,c]*dinv[s]
//                        + hW[n,c]*invdeg[n] + b[c]
__global__ __launch_bounds__(256) void k_gather(const float* __restrict__ hW,
        const int* __restrict__ csr, const int* __restrict__ off,
        const int* __restrict__ degi, const float* __restrict__ dinv,
        const float* __restrict__ invdeg, const float* __restrict__ bias,
        float* __restrict__ agg) {
    const int n = blockIdx.x;
    const int c = threadIdx.x;
    const int start = off[n];
    const int cnt = degi[n];
    __shared__ int   sidx[64];
    __shared__ float swht[64];
    float acc = 0.f;
    for (int k0 = 0; k0 < cnt; k0 += 64) {
        __syncthreads();
        if (c < 64 && k0 + c < cnt) {
            int s = csr[start + k0 + c];
            sidx[c] = s;
            swht[c] = dinv[s];
        }
        __syncthreads();
        int lim = min(64, cnt - k0);
        for (int k = 0; k < lim; ++k)
            acc += hW[(size_t)sidx[k] * HDIM + c] * swht[k];
    }
    agg[(size_t)n * HDIM + c] =
        acc * dinv[n] + hW[(size_t)n * HDIM + c] * invdeg[n] + bias[c];
}

// ---------------------------------------------------------------------------
// split-K flash attention fp32: one q-row per thread, SPLIT chunks of keys
__global__ __launch_bounds__(128) void k_attn_split(const float* __restrict__ qkv,
        float* __restrict__ pm, float* __restrict__ pl, float* __restrict__ po) {
    const int hd  = blockIdx.x;
    const int row = blockIdx.y * 128 + threadIdx.x;
    const int z   = blockIdx.z;
    const int tid = threadIdx.x;
    __shared__ float Kl[32 * 32];
    __shared__ float Vl[32 * 32];
    const float scale = 0.17677669529663687f;
    float q[32];
    {
        const float* qp = qkv + (size_t)row * 768 + hd * DH;
        #pragma unroll
        for (int w = 0; w < 8; ++w) {
            float4 v = *(const float4*)&qp[w * 4];
            q[w*4+0] = v.x * scale; q[w*4+1] = v.y * scale;
            q[w*4+2] = v.z * scale; q[w*4+3] = v.w * scale;
        }
    }
    float oa[32] = {};
    float m = -INFINITY, l = 0.f;

    for (int t = z * (KCH / 32); t < (z + 1) * (KCH / 32); ++t) {
        __syncthreads();
        #pragma unroll
        for (int f = tid; f < 256; f += 128) {
            int j = f >> 3, w = f & 7;
            size_t base = (size_t)(t * 32 + j) * 768 + hd * DH + w * 4;
            *(float4*)&Kl[j * 32 + w * 4] = *(const float4*)&qkv[base + 256];
            *(float4*)&Vl[j * 32 + w * 4] = *(const float4*)&qkv[base + 512];
        }
        __syncthreads();
        float sv[32];
        float smax = -INFINITY;
        #pragma unroll
        for (int j = 0; j < 32; ++j) {
            float acc = 0.f;
            #pragma unroll
            for (int w = 0; w < 8; ++w) {
                float4 kv = *(const float4*)&Kl[j * 32 + w * 4];
                acc += q[w*4+0]*kv.x + q[w*4+1]*kv.y + q[w*4+2]*kv.z + q[w*4+3]*kv.w;
            }
            sv[j] = acc;
            smax = fmaxf(smax, acc);
        }
        float mnew = fmaxf(m, smax);
        float corr = __expf(m - mnew);
        l *= corr;
        #pragma unroll
        for (int d = 0; d < 32; ++d) oa[d] *= corr;
        #pragma unroll
        for (int j = 0; j < 32; ++j) {
            float p = __expf(sv[j] - mnew);
            l += p;
            #pragma unroll
            for (int w = 0; w < 8; ++w) {
                float4 vv = *(const float4*)&Vl[j * 32 + w * 4];
                oa[w*4+0] += p*vv.x; oa[w*4+1] += p*vv.y;
                oa[w*4+2] += p*vv.z; oa[w*4+3] += p*vv.w;
            }
        }
        m = mnew;
    }
    const size_t idx = ((size_t)hd * NNODE + row) * SPLIT + z;
    pm[idx] = m;
    pl[idx] = l;
    float* pp = po + idx * 32;
    #pragma unroll
    for (int w = 0; w < 8; ++w) {
        float4 v = {oa[w*4+0], oa[w*4+1], oa[w*4+2], oa[w*4+3]};
        *(float4*)&pp[w * 4] = v;
    }
}

__global__ void k_attn_merge(const float* __restrict__ pm, const float* __restrict__ pl,
                             const float* __restrict__ po, float* __restrict__ o) {
    int idx = blockIdx.x * 256 + threadIdx.x;   // hd*N + row
    if (idx >= HEADS * NNODE) return;
    int hd = idx >> 12, row = idx & (NNODE - 1);
    float m0 = pm[idx*4+0], m1 = pm[idx*4+1], m2 = pm[idx*4+2], m3 = pm[idx*4+3];
    float M = fmaxf(fmaxf(m0, m1), fmaxf(m2, m3));
    float w0 = __expf(m0 - M), w1 = __expf(m1 - M);
    float w2 = __expf(m2 - M), w3 = __expf(m3 - M);
    float L = pl[idx*4+0]*w0 + pl[idx*4+1]*w1 + pl[idx*4+2]*w2 + pl[idx*4+3]*w3;
    float inv = 1.f / L;
    const float* p = po + (size_t)idx * (SPLIT * 32);
    float* op = o + (size_t)row * HDIM + hd * DH;
    #pragma unroll
    for (int w = 0; w < 8; ++w) {
        float4 a = *(const float4*)&p[w*4];
        float4 b = *(const float4*)&p[32 + w*4];
        float4 c = *(const float4*)&p[64 + w*4];
        float4 d = *(const float4*)&p[96 + w*4];
        float4 r;
        r.x = (a.x*w0 + b.x*w1 + c.x*w2 + d.x*w3) * inv;
        r.y = (a.y*w0 + b.y*w1 + c.y*w2 + d.y*w3) * inv;
        r.z = (a.z*w0 + b.z*w1 + c.z*w2 + d.z*w3) * inv;
        r.w = (a.w*w0 + b.w*w1 + c.w*w2 + d.w*w3) * inv;
        *(float4*)&op[w * 4] = r;
    }
}

// ---------------------------------------------------------------------------
__global__ __launch_bounds__(256) void k_heads(const float* __restrict__ h,
        const float* __restrict__ fp1w, const float* __restrict__ fp1b,
        const float* __restrict__ fp2w, const float* __restrict__ fp2b,
        const float* __restrict__ pd1w, const float* __restrict__ pd1b,
        const float* __restrict__ pd2w, const float* __restrict__ pd2b,
        float* __restrict__ out) {
    int n = blockIdx.x;
    int tid = threadIdx.x;
    __shared__ float hrow[256];
    __shared__ float t[256];
    __shared__ float logits[16];
    hrow[tid] = h[(size_t)n * HDIM + tid];
    __syncthreads();
    {
        int i = tid & 127;
        const float* wrow = (tid < 128) ? (fp1w + (size_t)i * 256) : (pd1w + (size_t)i * 256);
        float acc = 0.f;
        #pragma unroll 8
        for (int k = 0; k < 256; k += 4) {
            float4 wv = *(const float4*)&wrow[k];
            acc += hrow[k]*wv.x + hrow[k+1]*wv.y + hrow[k+2]*wv.z + hrow[k+3]*wv.w;
        }
        acc += (tid < 128) ? fp1b[i] : pd1b[i];
        t[tid] = fmaxf(acc, 0.f);
    }
    __syncthreads();
    if (tid < 13) {
        const float* wrow; const float* tt; float bb;
        if (tid < 3) { wrow = fp2w + tid * 128;      tt = t;       bb = fp2b[tid]; }
        else         { wrow = pd2w + (tid-3) * 128;  tt = t + 128; bb = pd2b[tid-3]; }
        float acc = bb;
        #pragma unroll 8
        for (int k = 0; k < 128; k += 4) {
            float4 wv = *(const float4*)&wrow[k];
            acc += tt[k]*wv.x + tt[k+1]*wv.y + tt[k+2]*wv.z + tt[k+3]*wv.w;
        }
        logits[tid] = acc;
    }
    __syncthreads();
    if (tid < 3) {
        float mx = fmaxf(logits[0], fmaxf(logits[1], logits[2]));
        float e0 = __expf(logits[0]-mx), e1 = __expf(logits[1]-mx), e2 = __expf(logits[2]-mx);
        float mine = (tid == 0) ? e0 : ((tid == 1) ? e1 : e2);
        out[(size_t)n * 3 + tid] = mine / (e0 + e1 + e2);
    } else if (tid < 13) {
        out[(size_t)NNODE * 3 + (size_t)n * 10 + (tid - 3)] =
            1.0f / (1.0f + __expf(-logits[tid]));
    }
}

// ---------------------------------------------------------------------------
extern "C" void kernel_launch(void* const* d_in, const int* in_sizes, int n_in,
                              void* d_out, int out_size, void* d_ws, size_t ws_size,
                              hipStream_t stream) {
    const float* x    = (const float*)d_in[0];
    const int*   ei   = (const int*)  d_in[1];
    const float* W1   = (const float*)d_in[2];
    const float* b1   = (const float*)d_in[3];
    const float* W2   = (const float*)d_in[4];
    const float* b2   = (const float*)d_in[5];
    const float* W3   = (const float*)d_in[6];
    const float* b3   = (const float*)d_in[7];
    const float* in_w = (const float*)d_in[8];
    const float* in_b = (const float*)d_in[9];
    const float* outw = (const float*)d_in[10];
    const float* outb = (const float*)d_in[11];
    const float* fp1w = (const float*)d_in[12];
    const float* fp1b = (const float*)d_in[13];
    const float* fp2w = (const float*)d_in[14];
    const float* fp2b = (const float*)d_in[15];
    const float* pd1w = (const float*)d_in[16];
    const float* pd1b = (const float*)d_in[17];
    const float* pd2w = (const float*)d_in[18];
    const float* pd2b = (const float*)d_in[19];
    float* out = (float*)d_out;

    const int E = in_sizes[1] / 2;

    // workspace layout
    char* w = (char*)d_ws;
    int*   degi   = (int*)w;                     w += (size_t)NNODE * 4;
    int*   off    = (int*)w;                     w += (size_t)NNODE * 4;
    int*   cursor = (int*)w;                     w += (size_t)NNODE * 4;
    int*   csr    = (int*)w;                     w += (size_t)E * 4;
    // align to 16B
    w = (char*)(((uintptr_t)w + 15) & ~(uintptr_t)15);
    float* dinv   = (float*)w;                   w += (size_t)NNODE * 4;
    float* invdeg = (float*)w;                   w += (size_t)NNODE * 4;
    float* bufA   = (float*)w;                   w += (size_t)NNODE * HDIM * 4;
    float* bufB   = (float*)w;                   w += (size_t)NNODE * HDIM * 4;
    float* bufC   = (float*)w;                   w += (size_t)NNODE * HDIM * 4;
    float* qkvb   = (float*)w;                   w += (size_t)NNODE * 768 * 4;
    float* pm     = (float*)w;                   w += (size_t)HEADS * NNODE * SPLIT * 4;
    float* pl     = (float*)w;                   w += (size_t)HEADS * NNODE * SPLIT * 4;
    float* po     = (float*)w;                   w += (size_t)HEADS * NNODE * SPLIT * 32 * 4;

    // CSR build + norms
    hipMemsetAsync(degi, 0, NNODE * sizeof(int), stream);
    k_deg<<<(E + 255) / 256, 256, 0, stream>>>(ei, degi, E);
    k_scan_norm<<<1, 256, 0, stream>>>(degi, off, cursor, dinv, invdeg);
    k_fill<<<(E + 255) / 256, 256, 0, stream>>>(ei, cursor, csr, E);

    dim3 g256(HDIM / 64, NNODE / 64);
    dim3 g768(768 / 64, NNODE / 64);

    // conv1
    k_gemm<DIN, false, false, false, false><<<g256, 256, 0, stream>>>(x, W1, nullptr, nullptr, bufA, HDIM);
    k_gather<<<NNODE, 256, 0, stream>>>(bufA, csr, off, degi, dinv, invdeg, b1, bufB);
    // conv2
    k_gemm<HDIM, false, true, false, false><<<g256, 256, 0, stream>>>(bufB, W2, nullptr, nullptr, bufA, HDIM);
    k_gather<<<NNODE, 256, 0, stream>>>(bufA, csr, off, degi, dinv, invdeg, b2, bufC);
    // conv3
    k_gemm<HDIM, false, true, false, false><<<g256, 256, 0, stream>>>(bufC, W3, nullptr, nullptr, bufA, HDIM);
    k_gather<<<NNODE, 256, 0, stream>>>(bufA, csr, off, degi, dinv, invdeg, b3, bufB);
    // h = bufB

    // MHA
    k_gemm<HDIM, true, false, true, false><<<g768, 256, 0, stream>>>(bufB, in_w, in_b, nullptr, qkvb, 768);
    k_attn_split<<<dim3(HEADS, NNODE / 128, SPLIT), 128, 0, stream>>>(qkvb, pm, pl, po);
    k_attn_merge<<<(HEADS * NNODE) / 256, 256, 0, stream>>>(pm, pl, po, bufA);
    k_gemm<HDIM, true, false, true, true><<<g256, 256, 0, stream>>>(bufA, outw, outb, bufB, bufC, HDIM);

    // heads
    k_heads<<<NNODE, 256, 0, stream>>>(bufC, fp1w, fp1b, fp2w, fp2b,
                                       pd1w, pd1b, pd2w, pd2b, out);
}

// Round 3
// 374.579 us; speedup vs baseline: 7.3096x; 1.9902x over previous
//
#include <hip/hip_runtime.h>
#include <math.h>

static constexpr int NNODE = 4096;
static constexpr int HDIM  = 256;
static constexpr int DIN   = 128;
static constexpr int HEADS = 8;

using short8 = __attribute__((ext_vector_type(8))) short;
using f32x4  = __attribute__((ext_vector_type(4))) float;

__device__ inline unsigned short bfr(float x) {   // RNE fp32->bf16
    union { float f; unsigned u; } v; v.f = x;
    unsigned r = v.u + 0x7FFFu + ((v.u >> 16) & 1u);
    return (unsigned short)(r >> 16);
}
__device__ inline unsigned pack2bf(float a, float b) {
    return (unsigned)bfr(a) | ((unsigned)bfr(b) << 16);
}

// ---------------------------------------------------------------------------
__global__ void k_deg(const int* __restrict__ ei, int* __restrict__ degi, int E) {
    int e = blockIdx.x * 256 + threadIdx.x;
    if (e < E) atomicAdd(&degi[ei[E + e]], 1);
}

__global__ __launch_bounds__(256) void k_scan_norm(const int* __restrict__ degi,
        int* __restrict__ off, int* __restrict__ cursor,
        float* __restrict__ dinv, float* __restrict__ invdeg) {
    __shared__ int partial[256];
    __shared__ int basesh[256];
    int t = threadIdx.x;
    int local[16];
    int s = 0;
    #pragma unroll
    for (int i = 0; i < 16; ++i) { local[i] = degi[t * 16 + i]; s += local[i]; }
    partial[t] = s;
    __syncthreads();
    if (t == 0) {
        int run = 0;
        for (int i = 0; i < 256; ++i) { basesh[i] = run; run += partial[i]; }
    }
    __syncthreads();
    int b = basesh[t];
    #pragma unroll
    for (int i = 0; i < 16; ++i) {
        int n = t * 16 + i;
        off[n] = b; cursor[n] = b; b += local[i];
        float d = (float)local[i] + 1.0f;
        dinv[n]   = rsqrtf(d);
        invdeg[n] = 1.0f / d;
    }
}

__global__ void k_fill(const int* __restrict__ ei, int* __restrict__ cursor,
                       int* __restrict__ csr, int E) {
    int e = blockIdx.x * 256 + threadIdx.x;
    if (e < E) {
        int d = ei[E + e];
        int p = atomicAdd(&cursor[d], 1);
        csr[p] = ei[e];
    }
}

// ---------------------------------------------------------------------------
// fp32 tiled GEMM: C[M=4096, Nout] = act(A) @ B (+bias) (+addsrc)
template<int K, bool TB, bool RELUA, bool BIAS, bool ADD>
__global__ __launch_bounds__(256) void k_gemm(const float* __restrict__ A,
                                              const float* __restrict__ B,
                                              const float* __restrict__ bias,
                                              const float* __restrict__ addsrc,
                                              float* __restrict__ C, int Nout) {
    __shared__ float As[16][68];
    __shared__ float Bs[16][64];
    const int tid = threadIdx.x;
    const int m0 = blockIdx.y * 64;
    const int n0 = blockIdx.x * 64;
    const int tx = tid & 15;
    const int ty = tid >> 4;
    const int ar = tid >> 2;
    const int aq = tid & 3;
    float acc[4][4] = {};

    for (int k0 = 0; k0 < K; k0 += 16) {
        __syncthreads();
        {
            float4 v = *(const float4*)&A[(size_t)(m0 + ar) * K + k0 + aq * 4];
            if (RELUA) {
                v.x = fmaxf(v.x, 0.f); v.y = fmaxf(v.y, 0.f);
                v.z = fmaxf(v.z, 0.f); v.w = fmaxf(v.w, 0.f);
            }
            As[aq*4+0][ar] = v.x; As[aq*4+1][ar] = v.y;
            As[aq*4+2][ar] = v.z; As[aq*4+3][ar] = v.w;
        }
        if (!TB) {
            int kk = tid >> 4, jq = tid & 15;
            float4 v = *(const float4*)&B[(size_t)(k0 + kk) * Nout + n0 + jq * 4];
            *(float4*)&Bs[kk][jq * 4] = v;
        } else {
            float4 v = *(const float4*)&B[(size_t)(n0 + ar) * K + k0 + aq * 4];
            Bs[aq*4+0][ar] = v.x; Bs[aq*4+1][ar] = v.y;
            Bs[aq*4+2][ar] = v.z; Bs[aq*4+3][ar] = v.w;
        }
        __syncthreads();
        #pragma unroll
        for (int kk = 0; kk < 16; ++kk) {
            float4 a = *(const float4*)&As[kk][ty * 4];
            float4 b = *(const float4*)&Bs[kk][tx * 4];
            float av[4] = {a.x, a.y, a.z, a.w};
            float bv[4] = {b.x, b.y, b.z, b.w};
            #pragma unroll
            for (int i = 0; i < 4; ++i)
                #pragma unroll
                for (int j = 0; j < 4; ++j)
                    acc[i][j] += av[i] * bv[j];
        }
    }
    #pragma unroll
    for (int i = 0; i < 4; ++i) {
        int row = m0 + ty * 4 + i;
        #pragma unroll
        for (int j = 0; j < 4; ++j) {
            int col = n0 + tx * 4 + j;
            float v = acc[i][j];
            if (BIAS) v += bias[col];
            size_t idx = (size_t)row * Nout + col;
            if (ADD) v += addsrc[idx];
            C[idx] = v;
        }
    }
}

// ---------------------------------------------------------------------------
// CSR gather
__global__ __launch_bounds__(256) void k_gather(const float* __restrict__ hW,
        const int* __restrict__ csr, const int* __restrict__ off,
        const int* __restrict__ degi, const float* __restrict__ dinv,
        const float* __restrict__ invdeg, const float* __restrict__ bias,
        float* __restrict__ agg) {
    const int n = blockIdx.x;
    const int c = threadIdx.x;
    const int start = off[n];
    const int cnt = degi[n];
    __shared__ int   sidx[64];
    __shared__ float swht[64];
    float acc = 0.f;
    for (int k0 = 0; k0 < cnt; k0 += 64) {
        __syncthreads();
        if (c < 64 && k0 + c < cnt) {
            int s = csr[start + k0 + c];
            sidx[c] = s;
            swht[c] = dinv[s];
        }
        __syncthreads();
        int lim = min(64, cnt - k0);
        for (int k = 0; k < lim; ++k)
            acc += hW[(size_t)sidx[k] * HDIM + c] * swht[k];
    }
    agg[(size_t)n * HDIM + c] =
        acc * dinv[n] + hW[(size_t)n * HDIM + c] * invdeg[n] + bias[c];
}

// ---------------------------------------------------------------------------
// qkv fp32 [4096][768] -> head-major bf16 Qh/Kh/Vh [8][4096][32]; Q pre-scaled
__global__ __launch_bounds__(256) void k_cvt(const float* __restrict__ qkv,
        unsigned short* __restrict__ qh, unsigned short* __restrict__ kh,
        unsigned short* __restrict__ vh) {
    int idx = blockIdx.x * 256 + threadIdx.x;     // 4096*96 total
    int row = idx / 96;
    int c0 = (idx - row * 96) * 8;
    int sec = c0 >> 8;                            // 0=q 1=k 2=v
    int cc = c0 & 255;
    int head = cc >> 5, dh = cc & 31;
    const float* p = qkv + (size_t)row * 768 + c0;
    float4 a = *(const float4*)p;
    float4 b = *(const float4*)(p + 4);
    float s = (sec == 0) ? 0.17677669529663687f : 1.0f;
    unsigned short* dst = (sec == 0 ? qh : (sec == 1 ? kh : vh))
                          + ((size_t)head * NNODE + row) * 32 + dh;
    short8 o;
    o[0]=(short)bfr(a.x*s); o[1]=(short)bfr(a.y*s); o[2]=(short)bfr(a.z*s); o[3]=(short)bfr(a.w*s);
    o[4]=(short)bfr(b.x*s); o[5]=(short)bfr(b.y*s); o[6]=(short)bfr(b.z*s); o[7]=(short)bfr(b.w*s);
    *(short8*)dst = o;
}

// ---------------------------------------------------------------------------
// MFMA flash attention. Block = 1 head x 64 q rows, 4 waves (16 q each).
// S^T = K·Q^T (16x16x32 mfma, A=K rows, B=Q rows), online softmax per
// q-column (shfl_xor 16/32), P^T via per-wave LDS, O^T = V^T·P^T.
__global__ __launch_bounds__(256) void k_attn_mfma(const unsigned short* __restrict__ qh,
        const unsigned short* __restrict__ kh, const unsigned short* __restrict__ vh,
        float* __restrict__ o) {
    const int hd = blockIdx.x;
    const int qb = blockIdx.y;
    const int tid = threadIdx.x;
    const int wave = tid >> 6, lane = tid & 63;
    const int ql = lane & 15, g = lane >> 4;

    __shared__ unsigned short Klds[64 * 40];      // [key][dh] pad 40
    __shared__ unsigned short Vt[32 * 72];        // [dh][key] pad 72
    __shared__ unsigned short Plds[4][16 * 72];   // per wave [q][key] pad 72

    const unsigned short* khh = kh + (size_t)hd * NNODE * 32;
    const unsigned short* vhh = vh + (size_t)hd * NNODE * 32;

    // Q fragment: B-operand, lane holds Q[q=ql][dh = g*8 .. g*8+7]
    short8 qf = *(const short8*)(qh + ((size_t)hd * NNODE + qb * 64 + wave * 16 + ql) * 32 + g * 8);

    f32x4 oa0 = {0.f, 0.f, 0.f, 0.f};   // O^T dh 0-15
    f32x4 oa1 = {0.f, 0.f, 0.f, 0.f};   // O^T dh 16-31
    float m = -INFINITY, l = 0.f;

    const int skey = tid >> 2, sdh = (tid & 3) * 8;   // K staging
    const int vkey = tid & 63, vdh = (tid >> 6) * 8;  // V staging

    for (int kt = 0; kt < NNODE / 64; ++kt) {
        __syncthreads();
        {   // stage K tile [64][32]
            short8 kv = *(const short8*)(khh + (size_t)(kt * 64 + skey) * 32 + sdh);
            *(short8*)&Klds[skey * 40 + sdh] = kv;
            // stage V^T tile [32][64]
            short8 vv = *(const short8*)(vhh + (size_t)(kt * 64 + vkey) * 32 + vdh);
            #pragma unroll
            for (int i = 0; i < 8; ++i)
                Vt[(vdh + i) * 72 + vkey] = (unsigned short)vv[i];
        }
        __syncthreads();

        // S^T[64k x 16q]: 4 mfmas
        f32x4 st[4];
        #pragma unroll
        for (int t = 0; t < 4; ++t) {
            short8 kf = *(const short8*)&Klds[(t * 16 + ql) * 40 + g * 8];
            st[t] = __builtin_amdgcn_mfma_f32_16x16x32_bf16(kf, qf, (f32x4){0.f,0.f,0.f,0.f}, 0, 0, 0);
        }

        // online softmax over the 64 keys of this tile (per q = ql)
        float mloc = -INFINITY;
        #pragma unroll
        for (int t = 0; t < 4; ++t) {
            mloc = fmaxf(mloc, fmaxf(fmaxf(st[t][0], st[t][1]), fmaxf(st[t][2], st[t][3])));
        }
        mloc = fmaxf(mloc, __shfl_xor(mloc, 16));
        mloc = fmaxf(mloc, __shfl_xor(mloc, 32));
        float mnew = fmaxf(m, mloc);
        float corr = __expf(m - mnew);
        float ll = 0.f;
        unsigned pw[8];
        #pragma unroll
        for (int t = 0; t < 4; ++t) {
            float p0 = __expf(st[t][0] - mnew);
            float p1 = __expf(st[t][1] - mnew);
            float p2 = __expf(st[t][2] - mnew);
            float p3 = __expf(st[t][3] - mnew);
            ll += (p0 + p1) + (p2 + p3);
            pw[t * 2 + 0] = pack2bf(p0, p1);
            pw[t * 2 + 1] = pack2bf(p2, p3);
        }
        ll += __shfl_xor(ll, 16);
        ll += __shfl_xor(ll, 32);
        l = l * corr + ll;
        oa0 *= corr;
        oa1 *= corr;
        m = mnew;

        // write P^T: lane's keys t*16 + 4g..4g+3 for q=ql
        #pragma unroll
        for (int t = 0; t < 4; ++t) {
            uint2 w2; w2.x = pw[t * 2 + 0]; w2.y = pw[t * 2 + 1];
            *(uint2*)&Plds[wave][ql * 72 + t * 16 + g * 4] = w2;
        }

        // O^T += V^T · P^T : 2 key-chunks x 2 dh-tiles
        #pragma unroll
        for (int c = 0; c < 2; ++c) {
            short8 pf = *(const short8*)&Plds[wave][ql * 72 + c * 32 + g * 8];
            short8 v0 = *(const short8*)&Vt[ql * 72 + c * 32 + g * 8];
            short8 v1 = *(const short8*)&Vt[(16 + ql) * 72 + c * 32 + g * 8];
            oa0 = __builtin_amdgcn_mfma_f32_16x16x32_bf16(v0, pf, oa0, 0, 0, 0);
            oa1 = __builtin_amdgcn_mfma_f32_16x16x32_bf16(v1, pf, oa1, 0, 0, 0);
        }
    }

    float linv = 1.f / l;
    float* op = o + (size_t)(qb * 64 + wave * 16 + ql) * HDIM + hd * 32;
    float4 r0 = {oa0[0] * linv, oa0[1] * linv, oa0[2] * linv, oa0[3] * linv};
    float4 r1 = {oa1[0] * linv, oa1[1] * linv, oa1[2] * linv, oa1[3] * linv};
    *(float4*)&op[g * 4] = r0;
    *(float4*)&op[16 + g * 4] = r1;
}

// ---------------------------------------------------------------------------
__global__ __launch_bounds__(256) void k_heads(const float* __restrict__ h,
        const float* __restrict__ fp1w, const float* __restrict__ fp1b,
        const float* __restrict__ fp2w, const float* __restrict__ fp2b,
        const float* __restrict__ pd1w, const float* __restrict__ pd1b,
        const float* __restrict__ pd2w, const float* __restrict__ pd2b,
        float* __restrict__ out) {
    int n = blockIdx.x;
    int tid = threadIdx.x;
    __shared__ float hrow[256];
    __shared__ float t[256];
    __shared__ float logits[16];
    hrow[tid] = h[(size_t)n * HDIM + tid];
    __syncthreads();
    {
        int i = tid & 127;
        const float* wrow = (tid < 128) ? (fp1w + (size_t)i * 256) : (pd1w + (size_t)i * 256);
        float acc = 0.f;
        #pragma unroll 8
        for (int k = 0; k < 256; k += 4) {
            float4 wv = *(const float4*)&wrow[k];
            acc += hrow[k]*wv.x + hrow[k+1]*wv.y + hrow[k+2]*wv.z + hrow[k+3]*wv.w;
        }
        acc += (tid < 128) ? fp1b[i] : pd1b[i];
        t[tid] = fmaxf(acc, 0.f);
    }
    __syncthreads();
    if (tid < 13) {
        const float* wrow; const float* tt; float bb;
        if (tid < 3) { wrow = fp2w + tid * 128;      tt = t;       bb = fp2b[tid]; }
        else         { wrow = pd2w + (tid-3) * 128;  tt = t + 128; bb = pd2b[tid-3]; }
        float acc = bb;
        #pragma unroll 8
        for (int k = 0; k < 128; k += 4) {
            float4 wv = *(const float4*)&wrow[k];
            acc += tt[k]*wv.x + tt[k+1]*wv.y + tt[k+2]*wv.z + tt[k+3]*wv.w;
        }
        logits[tid] = acc;
    }
    __syncthreads();
    if (tid < 3) {
        float mx = fmaxf(logits[0], fmaxf(logits[1], logits[2]));
        float e0 = __expf(logits[0]-mx), e1 = __expf(logits[1]-mx), e2 = __expf(logits[2]-mx);
        float mine = (tid == 0) ? e0 : ((tid == 1) ? e1 : e2);
        out[(size_t)n * 3 + tid] = mine / (e0 + e1 + e2);
    } else if (tid < 13) {
        out[(size_t)NNODE * 3 + (size_t)n * 10 + (tid - 3)] =
            1.0f / (1.0f + __expf(-logits[tid]));
    }
}

// ---------------------------------------------------------------------------
extern "C" void kernel_launch(void* const* d_in, const int* in_sizes, int n_in,
                              void* d_out, int out_size, void* d_ws, size_t ws_size,
                              hipStream_t stream) {
    const float* x    = (const float*)d_in[0];
    const int*   ei   = (const int*)  d_in[1];
    const float* W1   = (const float*)d_in[2];
    const float* b1   = (const float*)d_in[3];
    const float* W2   = (const float*)d_in[4];
    const float* b2   = (const float*)d_in[5];
    const float* W3   = (const float*)d_in[6];
    const float* b3   = (const float*)d_in[7];
    const float* in_w = (const float*)d_in[8];
    const float* in_b = (const float*)d_in[9];
    const float* outw = (const float*)d_in[10];
    const float* outb = (const float*)d_in[11];
    const float* fp1w = (const float*)d_in[12];
    const float* fp1b = (const float*)d_in[13];
    const float* fp2w = (const float*)d_in[14];
    const float* fp2b = (const float*)d_in[15];
    const float* pd1w = (const float*)d_in[16];
    const float* pd1b = (const float*)d_in[17];
    const float* pd2w = (const float*)d_in[18];
    const float* pd2b = (const float*)d_in[19];
    float* out = (float*)d_out;

    const int E = in_sizes[1] / 2;

    // workspace layout
    char* w = (char*)d_ws;
    int*   degi   = (int*)w;                     w += (size_t)NNODE * 4;
    int*   off    = (int*)w;                     w += (size_t)NNODE * 4;
    int*   cursor = (int*)w;                     w += (size_t)NNODE * 4;
    int*   csr    = (int*)w;                     w += (size_t)E * 4;
    w = (char*)(((uintptr_t)w + 255) & ~(uintptr_t)255);
    float* dinv   = (float*)w;                   w += (size_t)NNODE * 4;
    float* invdeg = (float*)w;                   w += (size_t)NNODE * 4;
    float* bufA   = (float*)w;                   w += (size_t)NNODE * HDIM * 4;
    float* bufB   = (float*)w;                   w += (size_t)NNODE * HDIM * 4;
    float* bufC   = (float*)w;                   w += (size_t)NNODE * HDIM * 4;
    float* qkvb   = (float*)w;                   w += (size_t)NNODE * 768 * 4;
    unsigned short* qh = (unsigned short*)w;     w += (size_t)HEADS * NNODE * 32 * 2;
    unsigned short* kh = (unsigned short*)w;     w += (size_t)HEADS * NNODE * 32 * 2;
    unsigned short* vh = (unsigned short*)w;     w += (size_t)HEADS * NNODE * 32 * 2;

    // CSR build + norms
    hipMemsetAsync(degi, 0, NNODE * sizeof(int), stream);
    k_deg<<<(E + 255) / 256, 256, 0, stream>>>(ei, degi, E);
    k_scan_norm<<<1, 256, 0, stream>>>(degi, off, cursor, dinv, invdeg);
    k_fill<<<(E + 255) / 256, 256, 0, stream>>>(ei, cursor, csr, E);

    dim3 g256(HDIM / 64, NNODE / 64);
    dim3 g768(768 / 64, NNODE / 64);

    // conv1
    k_gemm<DIN, false, false, false, false><<<g256, 256, 0, stream>>>(x, W1, nullptr, nullptr, bufA, HDIM);
    k_gather<<<NNODE, 256, 0, stream>>>(bufA, csr, off, degi, dinv, invdeg, b1, bufB);
    // conv2
    k_gemm<HDIM, false, true, false, false><<<g256, 256, 0, stream>>>(bufB, W2, nullptr, nullptr, bufA, HDIM);
    k_gather<<<NNODE, 256, 0, stream>>>(bufA, csr, off, degi, dinv, invdeg, b2, bufC);
    // conv3
    k_gemm<HDIM, false, true, false, false><<<g256, 256, 0, stream>>>(bufC, W3, nullptr, nullptr, bufA, HDIM);
    k_gather<<<NNODE, 256, 0, stream>>>(bufA, csr, off, degi, dinv, invdeg, b3, bufB);
    // h = bufB

    // MHA
    k_gemm<HDIM, true, false, true, false><<<g768, 256, 0, stream>>>(bufB, in_w, in_b, nullptr, qkvb, 768);
    k_cvt<<<(NNODE * 96) / 256, 256, 0, stream>>>(qkvb, qh, kh, vh);
    k_attn_mfma<<<dim3(HEADS, NNODE / 64), 256, 0, stream>>>(qh, kh, vh, bufA);
    k_gemm<HDIM, true, false, true, true><<<g256, 256, 0, stream>>>(bufA, outw, outb, bufB, bufC, HDIM);

    // heads
    k_heads<<<NNODE, 256, 0, stream>>>(bufC, fp1w, fp1b, fp2w, fp2b,
                                       pd1w, pd1b, pd2w, pd2b, out);
}

// Round 4
// 280.755 us; speedup vs baseline: 9.7523x; 1.3342x over previous
//
#include <hip/hip_runtime.h>
#include <math.h>

static constexpr int NNODE = 4096;
static constexpr int HDIM  = 256;
static constexpr int DIN   = 128;
static constexpr int HEADS = 8;

using short8 = __attribute__((ext_vector_type(8))) short;
using f32x4  = __attribute__((ext_vector_type(4))) float;

__device__ inline unsigned short bfr(float x) {   // RNE fp32->bf16
    union { float f; unsigned u; } v; v.f = x;
    unsigned r = v.u + 0x7FFFu + ((v.u >> 16) & 1u);
    return (unsigned short)(r >> 16);
}
__device__ inline unsigned pack2bf(float a, float b) {
    return (unsigned)bfr(a) | ((unsigned)bfr(b) << 16);
}

// ---------------------------------------------------------------------------
__global__ void k_deg(const int* __restrict__ ei, int* __restrict__ degi, int E) {
    int e = blockIdx.x * 256 + threadIdx.x;
    if (e < E) atomicAdd(&degi[ei[E + e]], 1);
}

__global__ __launch_bounds__(256) void k_scan_norm(const int* __restrict__ degi,
        int* __restrict__ off, int* __restrict__ cursor,
        float* __restrict__ dinv, float* __restrict__ invdeg) {
    __shared__ int partial[256];
    __shared__ int basesh[256];
    int t = threadIdx.x;
    int local[16];
    int s = 0;
    #pragma unroll
    for (int i = 0; i < 16; ++i) { local[i] = degi[t * 16 + i]; s += local[i]; }
    partial[t] = s;
    __syncthreads();
    if (t == 0) {
        int run = 0;
        for (int i = 0; i < 256; ++i) { basesh[i] = run; run += partial[i]; }
    }
    __syncthreads();
    int b = basesh[t];
    #pragma unroll
    for (int i = 0; i < 16; ++i) {
        int n = t * 16 + i;
        off[n] = b; cursor[n] = b; b += local[i];
        float d = (float)local[i] + 1.0f;
        dinv[n]   = rsqrtf(d);
        invdeg[n] = 1.0f / d;
    }
}

__global__ void k_fill(const int* __restrict__ ei, int* __restrict__ cursor,
                       int* __restrict__ csr, int E) {
    int e = blockIdx.x * 256 + threadIdx.x;
    if (e < E) {
        int d = ei[E + e];
        int p = atomicAdd(&cursor[d], 1);
        csr[p] = ei[e];
    }
}

// concat [fp1w; pd1w] -> wcat [256][256], biases -> bcat [256]
__global__ void k_concat_w(const float* __restrict__ fp1w, const float* __restrict__ pd1w,
                           const float* __restrict__ fp1b, const float* __restrict__ pd1b,
                           float* __restrict__ wcat, float* __restrict__ bcat) {
    int idx = blockIdx.x * 256 + threadIdx.x;   // 65536 total
    int row = idx >> 8, c = idx & 255;
    wcat[idx] = (row < 128) ? fp1w[(size_t)row * 256 + c]
                            : pd1w[(size_t)(row - 128) * 256 + c];
    if (idx < 256) bcat[idx] = (idx < 128) ? fp1b[idx] : pd1b[idx - 128];
}

// ---------------------------------------------------------------------------
// fp32 tiled GEMM: C[M=4096, Nout(=ldc)] = act(A) @ B (+bias) (+addsrc)
template<int K, bool TB, bool RELUA, bool BIAS, bool ADD>
__global__ __launch_bounds__(256) void k_gemm(const float* __restrict__ A,
                                              const float* __restrict__ B,
                                              const float* __restrict__ bias,
                                              const float* __restrict__ addsrc,
                                              float* __restrict__ C, int Nout) {
    __shared__ float As[16][68];
    __shared__ float Bs[16][64];
    const int tid = threadIdx.x;
    const int m0 = blockIdx.y * 64;
    const int n0 = blockIdx.x * 64;
    const int tx = tid & 15;
    const int ty = tid >> 4;
    const int ar = tid >> 2;
    const int aq = tid & 3;
    float acc[4][4] = {};

    for (int k0 = 0; k0 < K; k0 += 16) {
        __syncthreads();
        {
            float4 v = *(const float4*)&A[(size_t)(m0 + ar) * K + k0 + aq * 4];
            if (RELUA) {
                v.x = fmaxf(v.x, 0.f); v.y = fmaxf(v.y, 0.f);
                v.z = fmaxf(v.z, 0.f); v.w = fmaxf(v.w, 0.f);
            }
            As[aq*4+0][ar] = v.x; As[aq*4+1][ar] = v.y;
            As[aq*4+2][ar] = v.z; As[aq*4+3][ar] = v.w;
        }
        if (!TB) {
            int kk = tid >> 4, jq = tid & 15;
            float4 v = *(const float4*)&B[(size_t)(k0 + kk) * Nout + n0 + jq * 4];
            *(float4*)&Bs[kk][jq * 4] = v;
        } else {
            float4 v = *(const float4*)&B[(size_t)(n0 + ar) * K + k0 + aq * 4];
            Bs[aq*4+0][ar] = v.x; Bs[aq*4+1][ar] = v.y;
            Bs[aq*4+2][ar] = v.z; Bs[aq*4+3][ar] = v.w;
        }
        __syncthreads();
        #pragma unroll
        for (int kk = 0; kk < 16; ++kk) {
            float4 a = *(const float4*)&As[kk][ty * 4];
            float4 b = *(const float4*)&Bs[kk][tx * 4];
            float av[4] = {a.x, a.y, a.z, a.w};
            float bv[4] = {b.x, b.y, b.z, b.w};
            #pragma unroll
            for (int i = 0; i < 4; ++i)
                #pragma unroll
                for (int j = 0; j < 4; ++j)
                    acc[i][j] += av[i] * bv[j];
        }
    }
    #pragma unroll
    for (int i = 0; i < 4; ++i) {
        int row = m0 + ty * 4 + i;
        #pragma unroll
        for (int j = 0; j < 4; ++j) {
            int col = n0 + tx * 4 + j;
            float v = acc[i][j];
            if (BIAS) v += bias[col];
            size_t idx = (size_t)row * Nout + col;
            if (ADD) v += addsrc[idx];
            C[idx] = v;
        }
    }
}

// ---------------------------------------------------------------------------
// CSR gather
__global__ __launch_bounds__(256) void k_gather(const float* __restrict__ hW,
        const int* __restrict__ csr, const int* __restrict__ off,
        const int* __restrict__ degi, const float* __restrict__ dinv,
        const float* __restrict__ invdeg, const float* __restrict__ bias,
        float* __restrict__ agg) {
    const int n = blockIdx.x;
    const int c = threadIdx.x;
    const int start = off[n];
    const int cnt = degi[n];
    __shared__ int   sidx[64];
    __shared__ float swht[64];
    float acc = 0.f;
    for (int k0 = 0; k0 < cnt; k0 += 64) {
        __syncthreads();
        if (c < 64 && k0 + c < cnt) {
            int s = csr[start + k0 + c];
            sidx[c] = s;
            swht[c] = dinv[s];
        }
        __syncthreads();
        int lim = min(64, cnt - k0);
        for (int k = 0; k < lim; ++k)
            acc += hW[(size_t)sidx[k] * HDIM + c] * swht[k];
    }
    agg[(size_t)n * HDIM + c] =
        acc * dinv[n] + hW[(size_t)n * HDIM + c] * invdeg[n] + bias[c];
}

// ---------------------------------------------------------------------------
// qkv fp32 [4096][768] -> head-major bf16 Qh/Kh/Vh [8][4096][32]; Q pre-scaled
__global__ __launch_bounds__(256) void k_cvt(const float* __restrict__ qkv,
        unsigned short* __restrict__ qh, unsigned short* __restrict__ kh,
        unsigned short* __restrict__ vh) {
    int idx = blockIdx.x * 256 + threadIdx.x;     // 4096*96 total
    int row = idx / 96;
    int c0 = (idx - row * 96) * 8;
    int sec = c0 >> 8;                            // 0=q 1=k 2=v
    int cc = c0 & 255;
    int head = cc >> 5, dh = cc & 31;
    const float* p = qkv + (size_t)row * 768 + c0;
    float4 a = *(const float4*)p;
    float4 b = *(const float4*)(p + 4);
    float s = (sec == 0) ? 0.17677669529663687f : 1.0f;
    unsigned short* dst = (sec == 0 ? qh : (sec == 1 ? kh : vh))
                          + ((size_t)head * NNODE + row) * 32 + dh;
    short8 o;
    o[0]=(short)bfr(a.x*s); o[1]=(short)bfr(a.y*s); o[2]=(short)bfr(a.z*s); o[3]=(short)bfr(a.w*s);
    o[4]=(short)bfr(b.x*s); o[5]=(short)bfr(b.y*s); o[6]=(short)bfr(b.z*s); o[7]=(short)bfr(b.w*s);
    *(short8*)dst = o;
}

// ---------------------------------------------------------------------------
// MFMA flash attention. Block = 1 head x 64 q rows, 4 waves (16 q each).
__global__ __launch_bounds__(256) void k_attn_mfma(const unsigned short* __restrict__ qh,
        const unsigned short* __restrict__ kh, const unsigned short* __restrict__ vh,
        float* __restrict__ o) {
    const int hd = blockIdx.x;
    const int qb = blockIdx.y;
    const int tid = threadIdx.x;
    const int wave = tid >> 6, lane = tid & 63;
    const int ql = lane & 15, g = lane >> 4;

    __shared__ unsigned short Klds[64 * 40];
    __shared__ unsigned short Vt[32 * 72];
    __shared__ unsigned short Plds[4][16 * 72];

    const unsigned short* khh = kh + (size_t)hd * NNODE * 32;
    const unsigned short* vhh = vh + (size_t)hd * NNODE * 32;

    short8 qf = *(const short8*)(qh + ((size_t)hd * NNODE + qb * 64 + wave * 16 + ql) * 32 + g * 8);

    f32x4 oa0 = {0.f, 0.f, 0.f, 0.f};
    f32x4 oa1 = {0.f, 0.f, 0.f, 0.f};
    float m = -INFINITY, l = 0.f;

    const int skey = tid >> 2, sdh = (tid & 3) * 8;
    const int vkey = tid & 63, vdh = (tid >> 6) * 8;

    for (int kt = 0; kt < NNODE / 64; ++kt) {
        __syncthreads();
        {
            short8 kv = *(const short8*)(khh + (size_t)(kt * 64 + skey) * 32 + sdh);
            *(short8*)&Klds[skey * 40 + sdh] = kv;
            short8 vv = *(const short8*)(vhh + (size_t)(kt * 64 + vkey) * 32 + vdh);
            #pragma unroll
            for (int i = 0; i < 8; ++i)
                Vt[(vdh + i) * 72 + vkey] = (unsigned short)vv[i];
        }
        __syncthreads();

        f32x4 st[4];
        #pragma unroll
        for (int t = 0; t < 4; ++t) {
            short8 kf = *(const short8*)&Klds[(t * 16 + ql) * 40 + g * 8];
            st[t] = __builtin_amdgcn_mfma_f32_16x16x32_bf16(kf, qf, (f32x4){0.f,0.f,0.f,0.f}, 0, 0, 0);
        }

        float mloc = -INFINITY;
        #pragma unroll
        for (int t = 0; t < 4; ++t) {
            mloc = fmaxf(mloc, fmaxf(fmaxf(st[t][0], st[t][1]), fmaxf(st[t][2], st[t][3])));
        }
        mloc = fmaxf(mloc, __shfl_xor(mloc, 16));
        mloc = fmaxf(mloc, __shfl_xor(mloc, 32));
        float mnew = fmaxf(m, mloc);
        float corr = __expf(m - mnew);
        float ll = 0.f;
        unsigned pw[8];
        #pragma unroll
        for (int t = 0; t < 4; ++t) {
            float p0 = __expf(st[t][0] - mnew);
            float p1 = __expf(st[t][1] - mnew);
            float p2 = __expf(st[t][2] - mnew);
            float p3 = __expf(st[t][3] - mnew);
            ll += (p0 + p1) + (p2 + p3);
            pw[t * 2 + 0] = pack2bf(p0, p1);
            pw[t * 2 + 1] = pack2bf(p2, p3);
        }
        ll += __shfl_xor(ll, 16);
        ll += __shfl_xor(ll, 32);
        l = l * corr + ll;
        oa0 *= corr;
        oa1 *= corr;
        m = mnew;

        #pragma unroll
        for (int t = 0; t < 4; ++t) {
            uint2 w2; w2.x = pw[t * 2 + 0]; w2.y = pw[t * 2 + 1];
            *(uint2*)&Plds[wave][ql * 72 + t * 16 + g * 4] = w2;
        }

        #pragma unroll
        for (int c = 0; c < 2; ++c) {
            short8 pf = *(const short8*)&Plds[wave][ql * 72 + c * 32 + g * 8];
            short8 v0 = *(const short8*)&Vt[ql * 72 + c * 32 + g * 8];
            short8 v1 = *(const short8*)&Vt[(16 + ql) * 72 + c * 32 + g * 8];
            oa0 = __builtin_amdgcn_mfma_f32_16x16x32_bf16(v0, pf, oa0, 0, 0, 0);
            oa1 = __builtin_amdgcn_mfma_f32_16x16x32_bf16(v1, pf, oa1, 0, 0, 0);
        }
    }

    float linv = 1.f / l;
    float* op = o + (size_t)(qb * 64 + wave * 16 + ql) * HDIM + hd * 32;
    float4 r0 = {oa0[0] * linv, oa0[1] * linv, oa0[2] * linv, oa0[3] * linv};
    float4 r1 = {oa1[0] * linv, oa1[1] * linv, oa1[2] * linv, oa1[3] * linv};
    *(float4*)&op[g * 4] = r0;
    *(float4*)&op[16 + g * 4] = r1;
}

// ---------------------------------------------------------------------------
// heads layer-2 epilogue: one wave per node. th = [4096][256] pre-relu
// (cols 0..127 fp hidden, 128..255 pd hidden; bias already added by GEMM).
__global__ __launch_bounds__(256) void k_heads2(const float* __restrict__ th,
        const float* __restrict__ fp2w, const float* __restrict__ fp2b,
        const float* __restrict__ pd2w, const float* __restrict__ pd2b,
        float* __restrict__ out) {
    const int wave = threadIdx.x >> 6, lane = threadIdx.x & 63;
    const int n = blockIdx.x * 4 + wave;
    const int half = lane >> 5;        // 0 = fp head, 1 = pd head
    const int li = lane & 31;
    float4 h4 = *(const float4*)&th[(size_t)n * HDIM + half * 128 + li * 4];
    h4.x = fmaxf(h4.x, 0.f); h4.y = fmaxf(h4.y, 0.f);
    h4.z = fmaxf(h4.z, 0.f); h4.w = fmaxf(h4.w, 0.f);
    float lf[3];
    float lp[10];
    #pragma unroll
    for (int j = 0; j < 10; ++j) {
        float partial = 0.f;
        if (half == 0) {
            if (j < 3) {
                float4 wv = *(const float4*)&fp2w[j * 128 + li * 4];
                partial = h4.x*wv.x + h4.y*wv.y + h4.z*wv.z + h4.w*wv.w;
            }
        } else {
            float4 wv = *(const float4*)&pd2w[j * 128 + li * 4];
            partial = h4.x*wv.x + h4.y*wv.y + h4.z*wv.z + h4.w*wv.w;
        }
        #pragma unroll
        for (int d = 1; d < 32; d <<= 1) partial += __shfl_xor(partial, d);
        if (j < 3) lf[j] = partial;    // meaningful on lane 0
        lp[j] = partial;               // meaningful on lane 32
    }
    if (lane == 0) {
        float l0 = lf[0] + fp2b[0], l1 = lf[1] + fp2b[1], l2 = lf[2] + fp2b[2];
        float mx = fmaxf(l0, fmaxf(l1, l2));
        float e0 = __expf(l0 - mx), e1 = __expf(l1 - mx), e2 = __expf(l2 - mx);
        float inv = 1.f / (e0 + e1 + e2);
        out[(size_t)n * 3 + 0] = e0 * inv;
        out[(size_t)n * 3 + 1] = e1 * inv;
        out[(size_t)n * 3 + 2] = e2 * inv;
    } else if (lane == 32) {
        #pragma unroll
        for (int j = 0; j < 10; ++j)
            out[(size_t)NNODE * 3 + (size_t)n * 10 + j] =
                1.f / (1.f + __expf(-(lp[j] + pd2b[j])));
    }
}

// ---------------------------------------------------------------------------
extern "C" void kernel_launch(void* const* d_in, const int* in_sizes, int n_in,
                              void* d_out, int out_size, void* d_ws, size_t ws_size,
                              hipStream_t stream) {
    const float* x    = (const float*)d_in[0];
    const int*   ei   = (const int*)  d_in[1];
    const float* W1   = (const float*)d_in[2];
    const float* b1   = (const float*)d_in[3];
    const float* W2   = (const float*)d_in[4];
    const float* b2   = (const float*)d_in[5];
    const float* W3   = (const float*)d_in[6];
    const float* b3   = (const float*)d_in[7];
    const float* in_w = (const float*)d_in[8];
    const float* in_b = (const float*)d_in[9];
    const float* outw = (const float*)d_in[10];
    const float* outb = (const float*)d_in[11];
    const float* fp1w = (const float*)d_in[12];
    const float* fp1b = (const float*)d_in[13];
    const float* fp2w = (const float*)d_in[14];
    const float* fp2b = (const float*)d_in[15];
    const float* pd1w = (const float*)d_in[16];
    const float* pd1b = (const float*)d_in[17];
    const float* pd2w = (const float*)d_in[18];
    const float* pd2b = (const float*)d_in[19];
    float* out = (float*)d_out;

    const int E = in_sizes[1] / 2;

    // workspace layout
    char* w = (char*)d_ws;
    int*   degi   = (int*)w;                     w += (size_t)NNODE * 4;
    int*   off    = (int*)w;                     w += (size_t)NNODE * 4;
    int*   cursor = (int*)w;                     w += (size_t)NNODE * 4;
    int*   csr    = (int*)w;                     w += (size_t)E * 4;
    w = (char*)(((uintptr_t)w + 255) & ~(uintptr_t)255);
    float* dinv   = (float*)w;                   w += (size_t)NNODE * 4;
    float* invdeg = (float*)w;                   w += (size_t)NNODE * 4;
    float* wcat   = (float*)w;                   w += (size_t)HDIM * HDIM * 4;
    float* bcat   = (float*)w;                   w += (size_t)HDIM * 4;
    float* bufA   = (float*)w;                   w += (size_t)NNODE * HDIM * 4;
    float* bufB   = (float*)w;                   w += (size_t)NNODE * HDIM * 4;
    float* bufC   = (float*)w;                   w += (size_t)NNODE * HDIM * 4;
    float* qkvb   = (float*)w;                   w += (size_t)NNODE * 768 * 4;
    unsigned short* qh = (unsigned short*)w;     w += (size_t)HEADS * NNODE * 32 * 2;
    unsigned short* kh = (unsigned short*)w;     w += (size_t)HEADS * NNODE * 32 * 2;
    unsigned short* vh = (unsigned short*)w;     w += (size_t)HEADS * NNODE * 32 * 2;

    // CSR build + norms (+ weight concat for heads layer 1)
    hipMemsetAsync(degi, 0, NNODE * sizeof(int), stream);
    k_deg<<<(E + 255) / 256, 256, 0, stream>>>(ei, degi, E);
    k_scan_norm<<<1, 256, 0, stream>>>(degi, off, cursor, dinv, invdeg);
    k_fill<<<(E + 255) / 256, 256, 0, stream>>>(ei, cursor, csr, E);
    k_concat_w<<<256, 256, 0, stream>>>(fp1w, pd1w, fp1b, pd1b, wcat, bcat);

    dim3 g256(HDIM / 64, NNODE / 64);
    dim3 g768(768 / 64, NNODE / 64);

    // conv1
    k_gemm<DIN, false, false, false, false><<<g256, 256, 0, stream>>>(x, W1, nullptr, nullptr, bufA, HDIM);
    k_gather<<<NNODE, 256, 0, stream>>>(bufA, csr, off, degi, dinv, invdeg, b1, bufB);
    // conv2
    k_gemm<HDIM, false, true, false, false><<<g256, 256, 0, stream>>>(bufB, W2, nullptr, nullptr, bufA, HDIM);
    k_gather<<<NNODE, 256, 0, stream>>>(bufA, csr, off, degi, dinv, invdeg, b2, bufC);
    // conv3
    k_gemm<HDIM, false, true, false, false><<<g256, 256, 0, stream>>>(bufC, W3, nullptr, nullptr, bufA, HDIM);
    k_gather<<<NNODE, 256, 0, stream>>>(bufA, csr, off, degi, dinv, invdeg, b3, bufB);
    // h = bufB

    // MHA
    k_gemm<HDIM, true, false, true, false><<<g768, 256, 0, stream>>>(bufB, in_w, in_b, nullptr, qkvb, 768);
    k_cvt<<<(NNODE * 96) / 256, 256, 0, stream>>>(qkvb, qh, kh, vh);
    k_attn_mfma<<<dim3(HEADS, NNODE / 64), 256, 0, stream>>>(qh, kh, vh, bufA);
    k_gemm<HDIM, true, false, true, true><<<g256, 256, 0, stream>>>(bufA, outw, outb, bufB, bufC, HDIM);

    // MLP heads: layer 1 as GEMM into bufA (cols 0..127 fp, 128..255 pd)
    k_gemm<HDIM, true, false, true, false><<<dim3(4, 64), 256, 0, stream>>>(bufC, wcat, bcat, nullptr, bufA, HDIM);
    k_heads2<<<NNODE / 4, 256, 0, stream>>>(bufA, fp2w, fp2b, pd2w, pd2b, out);
}

// Round 5
// 208.087 us; speedup vs baseline: 13.1580x; 1.3492x over previous
//
#include <hip/hip_runtime.h>
#include <math.h>

static constexpr int NNODE = 4096;
static constexpr int HDIM  = 256;
static constexpr int DIN   = 128;
static constexpr int HEADS = 8;
static constexpr int SPLIT = 2;     // attention key-split

using short8 = __attribute__((ext_vector_type(8))) short;
using f32x4  = __attribute__((ext_vector_type(4))) float;

__device__ inline unsigned short bfr(float x) {   // RNE fp32->bf16
    union { float f; unsigned u; } v; v.f = x;
    unsigned r = v.u + 0x7FFFu + ((v.u >> 16) & 1u);
    return (unsigned short)(r >> 16);
}
__device__ inline unsigned cvt_pk_bf16(float lo, float hi) {
    unsigned r;
    asm("v_cvt_pk_bf16_f32 %0, %1, %2" : "=v"(r) : "v"(lo), "v"(hi));
    return r;
}

// ---------------------------------------------------------------------------
__global__ void k_deg(const int* __restrict__ ei, int* __restrict__ degi, int E) {
    int e = blockIdx.x * 256 + threadIdx.x;
    if (e < E) atomicAdd(&degi[ei[E + e]], 1);
}

__global__ __launch_bounds__(256) void k_scan_norm(const int* __restrict__ degi,
        int* __restrict__ off, int* __restrict__ cursor,
        float* __restrict__ dinv, float* __restrict__ invdeg) {
    __shared__ int partial[256];
    __shared__ int basesh[256];
    int t = threadIdx.x;
    int local[16];
    int s = 0;
    #pragma unroll
    for (int i = 0; i < 16; ++i) { local[i] = degi[t * 16 + i]; s += local[i]; }
    partial[t] = s;
    __syncthreads();
    if (t == 0) {
        int run = 0;
        for (int i = 0; i < 256; ++i) { basesh[i] = run; run += partial[i]; }
    }
    __syncthreads();
    int b = basesh[t];
    #pragma unroll
    for (int i = 0; i < 16; ++i) {
        int n = t * 16 + i;
        off[n] = b; cursor[n] = b; b += local[i];
        float d = (float)local[i] + 1.0f;
        dinv[n]   = rsqrtf(d);
        invdeg[n] = 1.0f / d;
    }
}

__global__ void k_fill(const int* __restrict__ ei, int* __restrict__ cursor,
                       int* __restrict__ csr, int E) {
    int e = blockIdx.x * 256 + threadIdx.x;
    if (e < E) {
        int d = ei[E + e];
        int p = atomicAdd(&cursor[d], 1);
        csr[p] = ei[e];
    }
}

// ---------------------------------------------------------------------------
// weight prep: convert to bf16 (+ transpose GCN weights to [N][K] layout),
// concat fp1/pd1 into wcat. Grid 1920x256 covers 491520 elements.
__global__ __launch_bounds__(256) void k_prep(
        const float* __restrict__ W1, const float* __restrict__ W2,
        const float* __restrict__ W3, const float* __restrict__ in_w,
        const float* __restrict__ outw, const float* __restrict__ fp1w,
        const float* __restrict__ pd1w, const float* __restrict__ fp1b,
        const float* __restrict__ pd1b,
        unsigned short* __restrict__ W1t, unsigned short* __restrict__ W2t,
        unsigned short* __restrict__ W3t, unsigned short* __restrict__ in_wb,
        unsigned short* __restrict__ outwb, unsigned short* __restrict__ wcatb,
        float* __restrict__ bcat) {
    int idx = blockIdx.x * 256 + threadIdx.x;
    if (idx < 32768) {                       // W1 [128][256] -> W1t [256][128]
        int c = idx >> 7, k = idx & 127;
        W1t[idx] = bfr(W1[(size_t)k * 256 + c]);
    } else if (idx < 98304) {                // W2 [256][256] -> W2t [256][256]
        int j = idx - 32768; int c = j >> 8, k = j & 255;
        W2t[j] = bfr(W2[(size_t)k * 256 + c]);
    } else if (idx < 163840) {
        int j = idx - 98304; int c = j >> 8, k = j & 255;
        W3t[j] = bfr(W3[(size_t)k * 256 + c]);
    } else if (idx < 360448) {               // in_w already [768][256]
        int j = idx - 163840;
        in_wb[j] = bfr(in_w[j]);
    } else if (idx < 425984) {               // outw already [256][256]
        int j = idx - 360448;
        outwb[j] = bfr(outw[j]);
    } else {                                 // wcat = [fp1w; pd1w]
        int j = idx - 425984;
        int row = j >> 8, k = j & 255;
        wcatb[j] = bfr(row < 128 ? fp1w[(size_t)row * 256 + k]
                                 : pd1w[(size_t)(row - 128) * 256 + k]);
        if (j < 256) bcat[j] = (j < 128) ? fp1b[j] : pd1b[j - 128];
    }
}

__global__ __launch_bounds__(256) void k_cvt_x(const float* __restrict__ x,
                                               unsigned short* __restrict__ xb) {
    int i = (blockIdx.x * 256 + threadIdx.x) * 8;   // 4096*128 total
    float4 a = *(const float4*)&x[i];
    float4 b = *(const float4*)&x[i + 4];
    short8 o;
    o[0]=(short)bfr(a.x); o[1]=(short)bfr(a.y); o[2]=(short)bfr(a.z); o[3]=(short)bfr(a.w);
    o[4]=(short)bfr(b.x); o[5]=(short)bfr(b.y); o[6]=(short)bfr(b.z); o[7]=(short)bfr(b.w);
    *(short8*)&xb[i] = o;
}

// ---------------------------------------------------------------------------
// bf16 MFMA GEMM: C[M=4096][Nout] = A_bf16 @ B_bf16^T (+bias) (+addsrc)
// A: [M][K] row-major bf16.  B: [Nout][K] row-major bf16 (torch layout).
// Block 256 thr = 4 waves; block tile 64(M) x 64(N); wave tile 16 x 64.
// EPI: 0 = fp32 out, 1 = bf16 out, 2 = qkv head-major bf16 (q pre-scaled).
template<int K, int EPI, bool BIAS, bool ADD>
__global__ __launch_bounds__(256) void k_bgemm(
        const unsigned short* __restrict__ A, const unsigned short* __restrict__ B,
        const float* __restrict__ bias, const float* __restrict__ addsrc,
        void* __restrict__ P0, void* __restrict__ P1, void* __restrict__ P2,
        int Nout) {
    const int lane = threadIdx.x & 63, wave = threadIdx.x >> 6;
    const int ql = lane & 15, g = lane >> 4;
    const int m0w = blockIdx.y * 64 + wave * 16;
    const int n0 = blockIdx.x * 64;
    const unsigned short* ap = A + (size_t)(m0w + ql) * K + g * 8;
    const unsigned short* bp = B + (size_t)(n0 + ql) * K + g * 8;

    f32x4 acc[4] = {{0,0,0,0},{0,0,0,0},{0,0,0,0},{0,0,0,0}};
    #pragma unroll 4
    for (int k0 = 0; k0 < K; k0 += 32) {
        short8 a = *(const short8*)(ap + k0);
        #pragma unroll
        for (int nt = 0; nt < 4; ++nt) {
            short8 b = *(const short8*)(bp + (size_t)nt * 16 * K + k0);
            acc[nt] = __builtin_amdgcn_mfma_f32_16x16x32_bf16(a, b, acc[nt], 0, 0, 0);
        }
    }
    #pragma unroll
    for (int nt = 0; nt < 4; ++nt) {
        const int col = n0 + nt * 16 + ql;
        const float bv = BIAS ? bias[col] : 0.f;
        if (EPI == 2) {
            const int sec = col >> 8, cc = col & 255;
            const int head = cc >> 5, dh = cc & 31;
            unsigned short* dst = (unsigned short*)(sec == 0 ? P0 : (sec == 1 ? P1 : P2));
            const float sc = (sec == 0) ? 0.17677669529663687f : 1.0f;
            #pragma unroll
            for (int i = 0; i < 4; ++i) {
                int row = m0w + g * 4 + i;
                dst[((size_t)head * NNODE + row) * 32 + dh] = bfr((acc[nt][i] + bv) * sc);
            }
        } else if (EPI == 1) {
            unsigned short* Cb = (unsigned short*)P0;
            #pragma unroll
            for (int i = 0; i < 4; ++i) {
                int row = m0w + g * 4 + i;
                float v = acc[nt][i] + bv;
                if (ADD) v += addsrc[(size_t)row * Nout + col];
                Cb[(size_t)row * Nout + col] = bfr(v);
            }
        } else {
            float* Cf = (float*)P0;
            #pragma unroll
            for (int i = 0; i < 4; ++i) {
                int row = m0w + g * 4 + i;
                float v = acc[nt][i] + bv;
                if (ADD) v += addsrc[(size_t)row * Nout + col];
                Cf[(size_t)row * Nout + col] = v;
            }
        }
    }
}

// ---------------------------------------------------------------------------
// CSR gather. MODE 0: write bf16(relu(val)) only. MODE 1: write fp32 + bf16.
template<int MODE>
__global__ __launch_bounds__(256) void k_gather(const float* __restrict__ hW,
        const int* __restrict__ csr, const int* __restrict__ off,
        const int* __restrict__ degi, const float* __restrict__ dinv,
        const float* __restrict__ invdeg, const float* __restrict__ bias,
        float* __restrict__ aggf, unsigned short* __restrict__ aggb) {
    const int n = blockIdx.x;
    const int c = threadIdx.x;
    const int start = off[n];
    const int cnt = degi[n];
    __shared__ int   sidx[64];
    __shared__ float swht[64];
    float acc = 0.f;
    for (int k0 = 0; k0 < cnt; k0 += 64) {
        __syncthreads();
        if (c < 64 && k0 + c < cnt) {
            int s = csr[start + k0 + c];
            sidx[c] = s;
            swht[c] = dinv[s];
        }
        __syncthreads();
        int lim = min(64, cnt - k0);
        for (int k = 0; k < lim; ++k)
            acc += hW[(size_t)sidx[k] * HDIM + c] * swht[k];
    }
    float val = acc * dinv[n] + hW[(size_t)n * HDIM + c] * invdeg[n] + bias[c];
    if (MODE == 0) {
        aggb[(size_t)n * HDIM + c] = bfr(fmaxf(val, 0.f));
    } else {
        aggf[(size_t)n * HDIM + c] = val;
        aggb[(size_t)n * HDIM + c] = bfr(val);
    }
}

// ---------------------------------------------------------------------------
// MFMA flash attention, split-K over keys. Block = 1 head x 64 q x 1 split.
__global__ __launch_bounds__(256) void k_attn_mfma(const unsigned short* __restrict__ qh,
        const unsigned short* __restrict__ kh, const unsigned short* __restrict__ vh,
        float* __restrict__ po, float* __restrict__ pm, float* __restrict__ pl) {
    const int hd = blockIdx.x;
    const int qb = blockIdx.y;
    const int z  = blockIdx.z;
    const int tid = threadIdx.x;
    const int wave = tid >> 6, lane = tid & 63;
    const int ql = lane & 15, g = lane >> 4;

    __shared__ unsigned short Klds[64 * 40];
    __shared__ unsigned short Vt[32 * 72];
    __shared__ unsigned short Plds[4][16 * 72];

    const unsigned short* khh = kh + (size_t)hd * NNODE * 32;
    const unsigned short* vhh = vh + (size_t)hd * NNODE * 32;
    const int row = qb * 64 + wave * 16 + ql;

    short8 qf = *(const short8*)(qh + ((size_t)hd * NNODE + row) * 32 + g * 8);

    f32x4 oa0 = {0,0,0,0}, oa1 = {0,0,0,0};
    float m = -INFINITY, l = 0.f;

    const int skey = tid >> 2, sdh = (tid & 3) * 8;
    const int vkey = tid & 63, vdh = (tid >> 6) * 8;

    const int t0 = z * (NNODE / 64 / SPLIT);
    const int t1 = t0 + (NNODE / 64 / SPLIT);
    for (int kt = t0; kt < t1; ++kt) {
        __syncthreads();
        {
            short8 kv = *(const short8*)(khh + (size_t)(kt * 64 + skey) * 32 + sdh);
            *(short8*)&Klds[skey * 40 + sdh] = kv;
            short8 vv = *(const short8*)(vhh + (size_t)(kt * 64 + vkey) * 32 + vdh);
            #pragma unroll
            for (int i = 0; i < 8; ++i)
                Vt[(vdh + i) * 72 + vkey] = (unsigned short)vv[i];
        }
        __syncthreads();

        f32x4 st[4];
        #pragma unroll
        for (int t = 0; t < 4; ++t) {
            short8 kf = *(const short8*)&Klds[(t * 16 + ql) * 40 + g * 8];
            st[t] = __builtin_amdgcn_mfma_f32_16x16x32_bf16(kf, qf, (f32x4){0.f,0.f,0.f,0.f}, 0, 0, 0);
        }

        float mloc = -INFINITY;
        #pragma unroll
        for (int t = 0; t < 4; ++t)
            mloc = fmaxf(mloc, fmaxf(fmaxf(st[t][0], st[t][1]), fmaxf(st[t][2], st[t][3])));
        mloc = fmaxf(mloc, __shfl_xor(mloc, 16));
        mloc = fmaxf(mloc, __shfl_xor(mloc, 32));

        // defer-max (T13): rescale only when the max grew significantly;
        // otherwise P is bounded by e^8, fp32/bf16 tolerate it.
        if (!__all(mloc <= m + 8.f)) {
            float mnew = fmaxf(m, mloc);
            float corr = __expf(m - mnew);   // first tile: exp(-inf)=0
            l *= corr;
            oa0 *= corr;
            oa1 *= corr;
            m = mnew;
        }

        float ll = 0.f;
        unsigned pw[8];
        #pragma unroll
        for (int t = 0; t < 4; ++t) {
            float p0 = __expf(st[t][0] - m);
            float p1 = __expf(st[t][1] - m);
            float p2 = __expf(st[t][2] - m);
            float p3 = __expf(st[t][3] - m);
            ll += (p0 + p1) + (p2 + p3);
            pw[t * 2 + 0] = cvt_pk_bf16(p0, p1);
            pw[t * 2 + 1] = cvt_pk_bf16(p2, p3);
        }
        ll += __shfl_xor(ll, 16);
        ll += __shfl_xor(ll, 32);
        l += ll;

        #pragma unroll
        for (int t = 0; t < 4; ++t) {
            uint2 w2; w2.x = pw[t * 2 + 0]; w2.y = pw[t * 2 + 1];
            *(uint2*)&Plds[wave][ql * 72 + t * 16 + g * 4] = w2;
        }

        #pragma unroll
        for (int c = 0; c < 2; ++c) {
            short8 pf = *(const short8*)&Plds[wave][ql * 72 + c * 32 + g * 8];
            short8 v0 = *(const short8*)&Vt[ql * 72 + c * 32 + g * 8];
            short8 v1 = *(const short8*)&Vt[(16 + ql) * 72 + c * 32 + g * 8];
            oa0 = __builtin_amdgcn_mfma_f32_16x16x32_bf16(v0, pf, oa0, 0, 0, 0);
            oa1 = __builtin_amdgcn_mfma_f32_16x16x32_bf16(v1, pf, oa1, 0, 0, 0);
        }
    }

    const size_t pidx = ((size_t)hd * NNODE + row) * SPLIT + z;
    float* pp = po + pidx * 32;
    float4 r0 = {oa0[0], oa0[1], oa0[2], oa0[3]};
    float4 r1 = {oa1[0], oa1[1], oa1[2], oa1[3]};
    *(float4*)&pp[g * 4]      = r0;
    *(float4*)&pp[16 + g * 4] = r1;
    if (g == 0) { pm[pidx] = m; pl[pidx] = l; }
}

__global__ __launch_bounds__(256) void k_attn_merge(const float* __restrict__ po,
        const float* __restrict__ pm, const float* __restrict__ pl,
        unsigned short* __restrict__ ob) {
    int idx = blockIdx.x * 256 + threadIdx.x;     // NNODE*HDIM
    int row = idx >> 8, c = idx & 255;
    int hd = c >> 5, dh = c & 31;
    size_t base = ((size_t)hd * NNODE + row) * SPLIT;
    float m0 = pm[base], m1 = pm[base + 1];
    float M = fmaxf(m0, m1);
    float w0 = __expf(m0 - M), w1 = __expf(m1 - M);
    float L = pl[base] * w0 + pl[base + 1] * w1;
    float v = (po[base * 32 + dh] * w0 + po[(base + 1) * 32 + dh] * w1) / L;
    ob[idx] = bfr(v);
}

// ---------------------------------------------------------------------------
// heads layer-2 epilogue: one wave per node; th = [4096][256] pre-relu fp32.
__global__ __launch_bounds__(256) void k_heads2(const float* __restrict__ th,
        const float* __restrict__ fp2w, const float* __restrict__ fp2b,
        const float* __restrict__ pd2w, const float* __restrict__ pd2b,
        float* __restrict__ out) {
    const int wave = threadIdx.x >> 6, lane = threadIdx.x & 63;
    const int n = blockIdx.x * 4 + wave;
    const int half = lane >> 5;        // 0 = fp head, 1 = pd head
    const int li = lane & 31;
    float4 h4 = *(const float4*)&th[(size_t)n * HDIM + half * 128 + li * 4];
    h4.x = fmaxf(h4.x, 0.f); h4.y = fmaxf(h4.y, 0.f);
    h4.z = fmaxf(h4.z, 0.f); h4.w = fmaxf(h4.w, 0.f);
    float lf[3];
    float lp[10];
    #pragma unroll
    for (int j = 0; j < 10; ++j) {
        float partial = 0.f;
        if (half == 0) {
            if (j < 3) {
                float4 wv = *(const float4*)&fp2w[j * 128 + li * 4];
                partial = h4.x*wv.x + h4.y*wv.y + h4.z*wv.z + h4.w*wv.w;
            }
        } else {
            float4 wv = *(const float4*)&pd2w[j * 128 + li * 4];
            partial = h4.x*wv.x + h4.y*wv.y + h4.z*wv.z + h4.w*wv.w;
        }
        #pragma unroll
        for (int d = 1; d < 32; d <<= 1) partial += __shfl_xor(partial, d);
        if (j < 3) lf[j] = partial;
        lp[j] = partial;
    }
    if (lane == 0) {
        float l0 = lf[0] + fp2b[0], l1 = lf[1] + fp2b[1], l2 = lf[2] + fp2b[2];
        float mx = fmaxf(l0, fmaxf(l1, l2));
        float e0 = __expf(l0 - mx), e1 = __expf(l1 - mx), e2 = __expf(l2 - mx);
        float inv = 1.f / (e0 + e1 + e2);
        out[(size_t)n * 3 + 0] = e0 * inv;
        out[(size_t)n * 3 + 1] = e1 * inv;
        out[(size_t)n * 3 + 2] = e2 * inv;
    } else if (lane == 32) {
        #pragma unroll
        for (int j = 0; j < 10; ++j)
            out[(size_t)NNODE * 3 + (size_t)n * 10 + j] =
                1.f / (1.f + __expf(-(lp[j] + pd2b[j])));
    }
}

// ---------------------------------------------------------------------------
extern "C" void kernel_launch(void* const* d_in, const int* in_sizes, int n_in,
                              void* d_out, int out_size, void* d_ws, size_t ws_size,
                              hipStream_t stream) {
    const float* x    = (const float*)d_in[0];
    const int*   ei   = (const int*)  d_in[1];
    const float* W1   = (const float*)d_in[2];
    const float* b1   = (const float*)d_in[3];
    const float* W2   = (const float*)d_in[4];
    const float* b2   = (const float*)d_in[5];
    const float* W3   = (const float*)d_in[6];
    const float* b3   = (const float*)d_in[7];
    const float* in_w = (const float*)d_in[8];
    const float* in_b = (const float*)d_in[9];
    const float* outw = (const float*)d_in[10];
    const float* outb = (const float*)d_in[11];
    const float* fp1w = (const float*)d_in[12];
    const float* fp1b = (const float*)d_in[13];
    const float* fp2w = (const float*)d_in[14];
    const float* fp2b = (const float*)d_in[15];
    const float* pd1w = (const float*)d_in[16];
    const float* pd1b = (const float*)d_in[17];
    const float* pd2w = (const float*)d_in[18];
    const float* pd2b = (const float*)d_in[19];
    float* out = (float*)d_out;

    const int E = in_sizes[1] / 2;

    // workspace layout (256B-aligned chunks)
    char* w = (char*)d_ws;
    auto alloc = [&](size_t bytes) {
        char* p = w; w += (bytes + 255) & ~(size_t)255; return p;
    };
    int*   degi   = (int*)alloc(NNODE * 4);
    int*   off    = (int*)alloc(NNODE * 4);
    int*   cursor = (int*)alloc(NNODE * 4);
    int*   csr    = (int*)alloc((size_t)E * 4);
    float* dinv   = (float*)alloc(NNODE * 4);
    float* invdeg = (float*)alloc(NNODE * 4);
    unsigned short* W1t   = (unsigned short*)alloc(256 * 128 * 2);
    unsigned short* W2t   = (unsigned short*)alloc(256 * 256 * 2);
    unsigned short* W3t   = (unsigned short*)alloc(256 * 256 * 2);
    unsigned short* in_wb = (unsigned short*)alloc(768 * 256 * 2);
    unsigned short* outwb = (unsigned short*)alloc(256 * 256 * 2);
    unsigned short* wcatb = (unsigned short*)alloc(256 * 256 * 2);
    float* bcat  = (float*)alloc(256 * 4);
    unsigned short* xb    = (unsigned short*)alloc((size_t)NNODE * DIN * 2);
    float* bufA  = (float*)alloc((size_t)NNODE * HDIM * 4);     // hW / th
    unsigned short* aggb1 = (unsigned short*)alloc((size_t)NNODE * HDIM * 2);
    unsigned short* aggb2 = (unsigned short*)alloc((size_t)NNODE * HDIM * 2);
    float* hf    = (float*)alloc((size_t)NNODE * HDIM * 4);     // h (fp32, residual)
    unsigned short* hb    = (unsigned short*)alloc((size_t)NNODE * HDIM * 2);
    unsigned short* qh    = (unsigned short*)alloc((size_t)HEADS * NNODE * 32 * 2);
    unsigned short* kh    = (unsigned short*)alloc((size_t)HEADS * NNODE * 32 * 2);
    unsigned short* vh    = (unsigned short*)alloc((size_t)HEADS * NNODE * 32 * 2);
    float* po    = (float*)alloc((size_t)HEADS * NNODE * SPLIT * 32 * 4);
    float* pm    = (float*)alloc((size_t)HEADS * NNODE * SPLIT * 4);
    float* pl    = (float*)alloc((size_t)HEADS * NNODE * SPLIT * 4);
    unsigned short* ob    = (unsigned short*)alloc((size_t)NNODE * HDIM * 2);
    unsigned short* hfinb = (unsigned short*)alloc((size_t)NNODE * HDIM * 2);

    // CSR build + norms + weight/x prep
    hipMemsetAsync(degi, 0, NNODE * sizeof(int), stream);
    k_deg<<<(E + 255) / 256, 256, 0, stream>>>(ei, degi, E);
    k_scan_norm<<<1, 256, 0, stream>>>(degi, off, cursor, dinv, invdeg);
    k_fill<<<(E + 255) / 256, 256, 0, stream>>>(ei, cursor, csr, E);
    k_prep<<<1920, 256, 0, stream>>>(W1, W2, W3, in_w, outw, fp1w, pd1w, fp1b, pd1b,
                                     W1t, W2t, W3t, in_wb, outwb, wcatb, bcat);
    k_cvt_x<<<(NNODE * DIN / 8) / 256, 256, 0, stream>>>(x, xb);

    dim3 g256(4, 64);
    dim3 g768(12, 64);

    // conv1
    k_bgemm<DIN, 0, false, false><<<g256, 256, 0, stream>>>(xb, W1t, nullptr, nullptr, bufA, nullptr, nullptr, HDIM);
    k_gather<0><<<NNODE, 256, 0, stream>>>(bufA, csr, off, degi, dinv, invdeg, b1, nullptr, aggb1);
    // conv2
    k_bgemm<HDIM, 0, false, false><<<g256, 256, 0, stream>>>(aggb1, W2t, nullptr, nullptr, bufA, nullptr, nullptr, HDIM);
    k_gather<0><<<NNODE, 256, 0, stream>>>(bufA, csr, off, degi, dinv, invdeg, b2, nullptr, aggb2);
    // conv3
    k_bgemm<HDIM, 0, false, false><<<g256, 256, 0, stream>>>(aggb2, W3t, nullptr, nullptr, bufA, nullptr, nullptr, HDIM);
    k_gather<1><<<NNODE, 256, 0, stream>>>(bufA, csr, off, degi, dinv, invdeg, b3, hf, hb);

    // MHA: qkv GEMM writes head-major bf16 q/k/v directly (q pre-scaled)
    k_bgemm<HDIM, 2, true, false><<<g768, 256, 0, stream>>>(hb, in_wb, in_b, nullptr, qh, kh, vh, 768);
    k_attn_mfma<<<dim3(HEADS, NNODE / 64, SPLIT), 256, 0, stream>>>(qh, kh, vh, po, pm, pl);
    k_attn_merge<<<(NNODE * HDIM) / 256, 256, 0, stream>>>(po, pm, pl, ob);
    // out-proj + residual -> bf16 h_final
    k_bgemm<HDIM, 1, true, true><<<g256, 256, 0, stream>>>(ob, outwb, outb, hf, hfinb, nullptr, nullptr, HDIM);

    // MLP heads: layer 1 as GEMM (fp32 out), layer 2 epilogue
    k_bgemm<HDIM, 0, true, false><<<g256, 256, 0, stream>>>(hfinb, wcatb, bcat, nullptr, bufA, nullptr, nullptr, HDIM);
    k_heads2<<<NNODE / 4, 256, 0, stream>>>(bufA, fp2w, fp2b, pd2w, pd2b, out);
}

// Round 6
// 206.405 us; speedup vs baseline: 13.2653x; 1.0081x over previous
//
#include <hip/hip_runtime.h>
#include <math.h>

static constexpr int NNODE = 4096;
static constexpr int HDIM  = 256;
static constexpr int DIN   = 128;
static constexpr int HEADS = 8;
static constexpr int SPLIT = 4;     // attention key-split

using short8 = __attribute__((ext_vector_type(8))) short;
using f32x4  = __attribute__((ext_vector_type(4))) float;

__device__ inline unsigned short bfr(float x) {   // RNE fp32->bf16
    union { float f; unsigned u; } v; v.f = x;
    unsigned r = v.u + 0x7FFFu + ((v.u >> 16) & 1u);
    return (unsigned short)(r >> 16);
}
__device__ inline float bf2f(unsigned short u) {
    union { unsigned u; float f; } v; v.u = (unsigned)u << 16; return v.f;
}
__device__ inline unsigned cvt_pk_bf16(float lo, float hi) {
    unsigned r;
    asm("v_cvt_pk_bf16_f32 %0, %1, %2" : "=v"(r) : "v"(lo), "v"(hi));
    return r;
}

// scale/sqrt(32) folded with log2(e): softmax computed in exp2 domain
static constexpr float QSCALE_LOG2 = 0.25503527f;   // 0.17677669529663687 * 1.4426950408889634

// ---------------------------------------------------------------------------
__global__ void k_deg(const int* __restrict__ ei, int* __restrict__ degi, int E) {
    int e = blockIdx.x * 256 + threadIdx.x;
    if (e < E) atomicAdd(&degi[ei[E + e]], 1);
}

__global__ __launch_bounds__(256) void k_scan_norm(const int* __restrict__ degi,
        int* __restrict__ off, int* __restrict__ cursor,
        float* __restrict__ dinv, float* __restrict__ invdeg) {
    __shared__ int partial[256];
    __shared__ int basesh[256];
    int t = threadIdx.x;
    int local[16];
    int s = 0;
    #pragma unroll
    for (int i = 0; i < 16; ++i) { local[i] = degi[t * 16 + i]; s += local[i]; }
    partial[t] = s;
    __syncthreads();
    if (t == 0) {
        int run = 0;
        for (int i = 0; i < 256; ++i) { basesh[i] = run; run += partial[i]; }
    }
    __syncthreads();
    int b = basesh[t];
    #pragma unroll
    for (int i = 0; i < 16; ++i) {
        int n = t * 16 + i;
        off[n] = b; cursor[n] = b; b += local[i];
        float d = (float)local[i] + 1.0f;
        dinv[n]   = rsqrtf(d);
        invdeg[n] = 1.0f / d;
    }
}

__global__ void k_fill(const int* __restrict__ ei, int* __restrict__ cursor,
                       int* __restrict__ csr, int E) {
    int e = blockIdx.x * 256 + threadIdx.x;
    if (e < E) {
        int d = ei[E + e];
        int p = atomicAdd(&cursor[d], 1);
        csr[p] = ei[e];
    }
}

// ---------------------------------------------------------------------------
// weight + x prep: bf16 convert (+ transpose GCN weights to [N][K]),
// concat fp1/pd1. Grid covers 557056 virtual slots.
__global__ __launch_bounds__(256) void k_prep(
        const float* __restrict__ W1, const float* __restrict__ W2,
        const float* __restrict__ W3, const float* __restrict__ in_w,
        const float* __restrict__ outw, const float* __restrict__ fp1w,
        const float* __restrict__ pd1w, const float* __restrict__ fp1b,
        const float* __restrict__ pd1b, const float* __restrict__ x,
        unsigned short* __restrict__ W1t, unsigned short* __restrict__ W2t,
        unsigned short* __restrict__ W3t, unsigned short* __restrict__ in_wb,
        unsigned short* __restrict__ outwb, unsigned short* __restrict__ wcatb,
        float* __restrict__ bcat, unsigned short* __restrict__ xb) {
    int idx = blockIdx.x * 256 + threadIdx.x;
    if (idx < 32768) {                       // W1 [128][256] -> W1t [256][128]
        int c = idx >> 7, k = idx & 127;
        W1t[idx] = bfr(W1[(size_t)k * 256 + c]);
    } else if (idx < 98304) {                // W2 [256][256] -> W2t
        int j = idx - 32768; int c = j >> 8, k = j & 255;
        W2t[j] = bfr(W2[(size_t)k * 256 + c]);
    } else if (idx < 163840) {
        int j = idx - 98304; int c = j >> 8, k = j & 255;
        W3t[j] = bfr(W3[(size_t)k * 256 + c]);
    } else if (idx < 360448) {               // in_w already [768][256]
        int j = idx - 163840;
        in_wb[j] = bfr(in_w[j]);
    } else if (idx < 425984) {               // outw already [256][256]
        int j = idx - 360448;
        outwb[j] = bfr(outw[j]);
    } else if (idx < 491520) {               // wcat = [fp1w; pd1w]
        int j = idx - 425984;
        int row = j >> 8, k = j & 255;
        wcatb[j] = bfr(row < 128 ? fp1w[(size_t)row * 256 + k]
                                 : pd1w[(size_t)(row - 128) * 256 + k]);
        if (j < 256) bcat[j] = (j < 128) ? fp1b[j] : pd1b[j - 128];
    } else if (idx < 557056) {               // x -> bf16, 8 elems/thread
        int i = (idx - 491520) * 8;
        float4 a = *(const float4*)&x[i];
        float4 b = *(const float4*)&x[i + 4];
        short8 o;
        o[0]=(short)bfr(a.x); o[1]=(short)bfr(a.y); o[2]=(short)bfr(a.z); o[3]=(short)bfr(a.w);
        o[4]=(short)bfr(b.x); o[5]=(short)bfr(b.y); o[6]=(short)bfr(b.z); o[7]=(short)bfr(b.w);
        *(short8*)&xb[i] = o;
    }
}

// ---------------------------------------------------------------------------
// bf16 MFMA GEMM: C[M=4096][Nout] = A_bf16 @ B_bf16^T (+bias) (+addsrc)
// A: [M][K] bf16. B: [Nout][K] bf16 (torch layout).
// Block 256 = 4 waves; block tile 64(M) x 32(N); wave tile 16 x 32.
// EPI: 0 = fp32 out, 1 = bf16 out, 2 = qkv head-major bf16 (q pre-scaled log2).
template<int K, int EPI, bool BIAS, bool ADD>
__global__ __launch_bounds__(256) void k_bgemm(
        const unsigned short* __restrict__ A, const unsigned short* __restrict__ B,
        const float* __restrict__ bias, const float* __restrict__ addsrc,
        void* __restrict__ P0, void* __restrict__ P1, void* __restrict__ P2,
        int Nout) {
    const int lane = threadIdx.x & 63, wave = threadIdx.x >> 6;
    const int ql = lane & 15, g = lane >> 4;
    const int m0w = blockIdx.y * 64 + wave * 16;
    const int n0 = blockIdx.x * 32;
    const unsigned short* ap = A + (size_t)(m0w + ql) * K + g * 8;
    const unsigned short* bp = B + (size_t)(n0 + ql) * K + g * 8;

    f32x4 acc[2] = {{0,0,0,0},{0,0,0,0}};
    #pragma unroll
    for (int k0 = 0; k0 < K; k0 += 32) {
        short8 a = *(const short8*)(ap + k0);
        #pragma unroll
        for (int nt = 0; nt < 2; ++nt) {
            short8 b = *(const short8*)(bp + (size_t)nt * 16 * K + k0);
            acc[nt] = __builtin_amdgcn_mfma_f32_16x16x32_bf16(a, b, acc[nt], 0, 0, 0);
        }
    }
    #pragma unroll
    for (int nt = 0; nt < 2; ++nt) {
        const int col = n0 + nt * 16 + ql;
        const float bv = BIAS ? bias[col] : 0.f;
        if (EPI == 2) {
            const int sec = col >> 8, cc = col & 255;
            const int head = cc >> 5, dh = cc & 31;
            unsigned short* dst = (unsigned short*)(sec == 0 ? P0 : (sec == 1 ? P1 : P2));
            const float sc = (sec == 0) ? QSCALE_LOG2 : 1.0f;
            #pragma unroll
            for (int i = 0; i < 4; ++i) {
                int row = m0w + g * 4 + i;
                dst[((size_t)head * NNODE + row) * 32 + dh] = bfr((acc[nt][i] + bv) * sc);
            }
        } else if (EPI == 1) {
            unsigned short* Cb = (unsigned short*)P0;
            #pragma unroll
            for (int i = 0; i < 4; ++i) {
                int row = m0w + g * 4 + i;
                float v = acc[nt][i] + bv;
                if (ADD) v += addsrc[(size_t)row * Nout + col];
                Cb[(size_t)row * Nout + col] = bfr(v);
            }
        } else {
            float* Cf = (float*)P0;
            #pragma unroll
            for (int i = 0; i < 4; ++i) {
                int row = m0w + g * 4 + i;
                float v = acc[nt][i] + bv;
                if (ADD) v += addsrc[(size_t)row * Nout + col];
                Cf[(size_t)row * Nout + col] = v;
            }
        }
    }
}

// ---------------------------------------------------------------------------
// CSR gather over bf16 hW. MODE 0: write bf16(relu(val)). MODE 1: fp32 + bf16.
template<int MODE>
__global__ __launch_bounds__(256) void k_gather(const unsigned short* __restrict__ hW,
        const int* __restrict__ csr, const int* __restrict__ off,
        const int* __restrict__ degi, const float* __restrict__ dinv,
        const float* __restrict__ invdeg, const float* __restrict__ bias,
        float* __restrict__ aggf, unsigned short* __restrict__ aggb) {
    const int n = blockIdx.x;
    const int c = threadIdx.x;
    const int start = off[n];
    const int cnt = degi[n];
    __shared__ int   sidx[64];
    __shared__ float swht[64];
    float acc = 0.f;
    for (int k0 = 0; k0 < cnt; k0 += 64) {
        __syncthreads();
        if (c < 64 && k0 + c < cnt) {
            int s = csr[start + k0 + c];
            sidx[c] = s;
            swht[c] = dinv[s];
        }
        __syncthreads();
        int lim = min(64, cnt - k0);
        for (int k = 0; k < lim; ++k)
            acc += bf2f(hW[(size_t)sidx[k] * HDIM + c]) * swht[k];
    }
    float val = acc * dinv[n] + bf2f(hW[(size_t)n * HDIM + c]) * invdeg[n] + bias[c];
    if (MODE == 0) {
        aggb[(size_t)n * HDIM + c] = bfr(fmaxf(val, 0.f));
    } else {
        aggf[(size_t)n * HDIM + c] = val;
        aggb[(size_t)n * HDIM + c] = bfr(val);
    }
}

// ---------------------------------------------------------------------------
// MFMA flash attention, split-K. Block = 1 head x 64 q x 1 of 4 splits.
// K read direct from L2 (no staging); V double-buffered, 1 barrier/iter.
// Softmax in log2 domain (Q pre-scaled by scale*log2e).
__global__ __launch_bounds__(256) void k_attn_mfma(const unsigned short* __restrict__ qh,
        const unsigned short* __restrict__ kh, const unsigned short* __restrict__ vh,
        unsigned short* __restrict__ po, float* __restrict__ pm, float* __restrict__ pl) {
    const int hd = blockIdx.x;
    const int qb = blockIdx.y;
    const int z  = blockIdx.z;
    const int tid = threadIdx.x;
    const int wave = tid >> 6, lane = tid & 63;
    const int ql = lane & 15, g = lane >> 4;

    __shared__ unsigned short Vt[2][32 * 72];     // [dh][key] pad 72
    __shared__ unsigned short Plds[4][16 * 72];   // per wave [q][key] pad 72

    const unsigned short* khh = kh + (size_t)hd * NNODE * 32;
    const unsigned short* vhh = vh + (size_t)hd * NNODE * 32;
    const int row = qb * 64 + wave * 16 + ql;
    short8 qf = *(const short8*)(qh + ((size_t)hd * NNODE + row) * 32 + g * 8);

    f32x4 oa0 = {0,0,0,0}, oa1 = {0,0,0,0};
    float m = -INFINITY, l = 0.f;

    const int vkey = tid & 63, vdh = (tid >> 6) * 8;
    const int TPS = NNODE / 64 / SPLIT;
    const int t0 = z * TPS;

    {   // prologue: stage V tile t0 into buf 0
        short8 vv = *(const short8*)(vhh + (size_t)(t0 * 64 + vkey) * 32 + vdh);
        #pragma unroll
        for (int i = 0; i < 8; ++i) Vt[0][(vdh + i) * 72 + vkey] = (unsigned short)vv[i];
    }
    __syncthreads();
    int cur = 0;

    for (int kt = t0; kt < t0 + TPS; ++kt) {
        if (kt + 1 < t0 + TPS) {   // prefetch next V tile into the other buffer
            short8 vv = *(const short8*)(vhh + (size_t)((kt + 1) * 64 + vkey) * 32 + vdh);
            #pragma unroll
            for (int i = 0; i < 8; ++i) Vt[cur ^ 1][(vdh + i) * 72 + vkey] = (unsigned short)vv[i];
        }

        // S^T[64k x 16q]: K fragments straight from global (L2-resident)
        f32x4 st[4];
        #pragma unroll
        for (int t = 0; t < 4; ++t) {
            short8 kf = *(const short8*)(khh + (size_t)(kt * 64 + t * 16 + ql) * 32 + g * 8);
            st[t] = __builtin_amdgcn_mfma_f32_16x16x32_bf16(kf, qf, (f32x4){0,0,0,0}, 0, 0, 0);
        }

        float mloc = -INFINITY;
        #pragma unroll
        for (int t = 0; t < 4; ++t)
            mloc = fmaxf(mloc, fmaxf(fmaxf(st[t][0], st[t][1]), fmaxf(st[t][2], st[t][3])));
        mloc = fmaxf(mloc, __shfl_xor(mloc, 16));
        mloc = fmaxf(mloc, __shfl_xor(mloc, 32));

        // defer-max (T13, log2 units): P bounded by 2^8 when deferred
        if (!__all(mloc <= m + 8.f)) {
            float mnew = fmaxf(m, mloc);
            float corr = exp2f(m - mnew);   // first tile: exp2(-inf)=0
            l *= corr; oa0 *= corr; oa1 *= corr; m = mnew;
        }

        float ll = 0.f;
        unsigned pw[8];
        #pragma unroll
        for (int t = 0; t < 4; ++t) {
            float p0 = exp2f(st[t][0] - m);
            float p1 = exp2f(st[t][1] - m);
            float p2 = exp2f(st[t][2] - m);
            float p3 = exp2f(st[t][3] - m);
            ll += (p0 + p1) + (p2 + p3);
            pw[t * 2 + 0] = cvt_pk_bf16(p0, p1);
            pw[t * 2 + 1] = cvt_pk_bf16(p2, p3);
        }
        ll += __shfl_xor(ll, 16);
        ll += __shfl_xor(ll, 32);
        l += ll;

        #pragma unroll
        for (int t = 0; t < 4; ++t) {
            uint2 w2; w2.x = pw[t * 2 + 0]; w2.y = pw[t * 2 + 1];
            *(uint2*)&Plds[wave][ql * 72 + t * 16 + g * 4] = w2;
        }

        #pragma unroll
        for (int c = 0; c < 2; ++c) {
            short8 pf = *(const short8*)&Plds[wave][ql * 72 + c * 32 + g * 8];
            short8 v0 = *(const short8*)&Vt[cur][ql * 72 + c * 32 + g * 8];
            short8 v1 = *(const short8*)&Vt[cur][(16 + ql) * 72 + c * 32 + g * 8];
            oa0 = __builtin_amdgcn_mfma_f32_16x16x32_bf16(v0, pf, oa0, 0, 0, 0);
            oa1 = __builtin_amdgcn_mfma_f32_16x16x32_bf16(v1, pf, oa1, 0, 0, 0);
        }
        __syncthreads();   // single barrier: Vt[cur^1] staged, Vt[cur] reads done
        cur ^= 1;
    }

    const size_t pidx = ((size_t)hd * NNODE + row) * SPLIT + z;
    unsigned short* pp = po + pidx * 32;
    uint2 r0, r1;
    r0.x = cvt_pk_bf16(oa0[0], oa0[1]); r0.y = cvt_pk_bf16(oa0[2], oa0[3]);
    r1.x = cvt_pk_bf16(oa1[0], oa1[1]); r1.y = cvt_pk_bf16(oa1[2], oa1[3]);
    *(uint2*)&pp[g * 4]      = r0;
    *(uint2*)&pp[16 + g * 4] = r1;
    if (g == 0) { pm[pidx] = m; pl[pidx] = l; }
}

__global__ __launch_bounds__(256) void k_attn_merge(const unsigned short* __restrict__ po,
        const float* __restrict__ pm, const float* __restrict__ pl,
        unsigned short* __restrict__ ob) {
    int idx = blockIdx.x * 256 + threadIdx.x;     // NNODE*HDIM
    int row = idx >> 8, c = idx & 255;
    int hd = c >> 5, dh = c & 31;
    size_t b4 = ((size_t)hd * NNODE + row) * SPLIT;
    float m0 = pm[b4+0], m1 = pm[b4+1], m2 = pm[b4+2], m3 = pm[b4+3];
    float M = fmaxf(fmaxf(m0, m1), fmaxf(m2, m3));
    float w0 = exp2f(m0 - M), w1 = exp2f(m1 - M);
    float w2 = exp2f(m2 - M), w3 = exp2f(m3 - M);
    float L = pl[b4]*w0 + pl[b4+1]*w1 + pl[b4+2]*w2 + pl[b4+3]*w3;
    float v = bf2f(po[(b4+0)*32 + dh])*w0 + bf2f(po[(b4+1)*32 + dh])*w1
            + bf2f(po[(b4+2)*32 + dh])*w2 + bf2f(po[(b4+3)*32 + dh])*w3;
    ob[idx] = bfr(v / L);
}

// ---------------------------------------------------------------------------
// heads layer-2 epilogue: one wave per node; th = [4096][256] pre-relu fp32.
__global__ __launch_bounds__(256) void k_heads2(const float* __restrict__ th,
        const float* __restrict__ fp2w, const float* __restrict__ fp2b,
        const float* __restrict__ pd2w, const float* __restrict__ pd2b,
        float* __restrict__ out) {
    const int wave = threadIdx.x >> 6, lane = threadIdx.x & 63;
    const int n = blockIdx.x * 4 + wave;
    const int half = lane >> 5;        // 0 = fp head, 1 = pd head
    const int li = lane & 31;
    float4 h4 = *(const float4*)&th[(size_t)n * HDIM + half * 128 + li * 4];
    h4.x = fmaxf(h4.x, 0.f); h4.y = fmaxf(h4.y, 0.f);
    h4.z = fmaxf(h4.z, 0.f); h4.w = fmaxf(h4.w, 0.f);
    float lf[3];
    float lp[10];
    #pragma unroll
    for (int j = 0; j < 10; ++j) {
        float partial = 0.f;
        if (half == 0) {
            if (j < 3) {
                float4 wv = *(const float4*)&fp2w[j * 128 + li * 4];
                partial = h4.x*wv.x + h4.y*wv.y + h4.z*wv.z + h4.w*wv.w;
            }
        } else {
            float4 wv = *(const float4*)&pd2w[j * 128 + li * 4];
            partial = h4.x*wv.x + h4.y*wv.y + h4.z*wv.z + h4.w*wv.w;
        }
        #pragma unroll
        for (int d = 1; d < 32; d <<= 1) partial += __shfl_xor(partial, d);
        if (j < 3) lf[j] = partial;
        lp[j] = partial;
    }
    if (lane == 0) {
        float l0 = lf[0] + fp2b[0], l1 = lf[1] + fp2b[1], l2 = lf[2] + fp2b[2];
        float mx = fmaxf(l0, fmaxf(l1, l2));
        float e0 = __expf(l0 - mx), e1 = __expf(l1 - mx), e2 = __expf(l2 - mx);
        float inv = 1.f / (e0 + e1 + e2);
        out[(size_t)n * 3 + 0] = e0 * inv;
        out[(size_t)n * 3 + 1] = e1 * inv;
        out[(size_t)n * 3 + 2] = e2 * inv;
    } else if (lane == 32) {
        #pragma unroll
        for (int j = 0; j < 10; ++j)
            out[(size_t)NNODE * 3 + (size_t)n * 10 + j] =
                1.f / (1.f + __expf(-(lp[j] + pd2b[j])));
    }
}

// ---------------------------------------------------------------------------
extern "C" void kernel_launch(void* const* d_in, const int* in_sizes, int n_in,
                              void* d_out, int out_size, void* d_ws, size_t ws_size,
                              hipStream_t stream) {
    const float* x    = (const float*)d_in[0];
    const int*   ei   = (const int*)  d_in[1];
    const float* W1   = (const float*)d_in[2];
    const float* b1   = (const float*)d_in[3];
    const float* W2   = (const float*)d_in[4];
    const float* b2   = (const float*)d_in[5];
    const float* W3   = (const float*)d_in[6];
    const float* b3   = (const float*)d_in[7];
    const float* in_w = (const float*)d_in[8];
    const float* in_b = (const float*)d_in[9];
    const float* outw = (const float*)d_in[10];
    const float* outb = (const float*)d_in[11];
    const float* fp1w = (const float*)d_in[12];
    const float* fp1b = (const float*)d_in[13];
    const float* fp2w = (const float*)d_in[14];
    const float* fp2b = (const float*)d_in[15];
    const float* pd1w = (const float*)d_in[16];
    const float* pd1b = (const float*)d_in[17];
    const float* pd2w = (const float*)d_in[18];
    const float* pd2b = (const float*)d_in[19];
    float* out = (float*)d_out;

    const int E = in_sizes[1] / 2;

    // workspace layout (256B-aligned chunks)
    char* w = (char*)d_ws;
    auto alloc = [&](size_t bytes) {
        char* p = w; w += (bytes + 255) & ~(size_t)255; return p;
    };
    int*   degi   = (int*)alloc(NNODE * 4);
    int*   off    = (int*)alloc(NNODE * 4);
    int*   cursor = (int*)alloc(NNODE * 4);
    int*   csr    = (int*)alloc((size_t)E * 4);
    float* dinv   = (float*)alloc(NNODE * 4);
    float* invdeg = (float*)alloc(NNODE * 4);
    unsigned short* W1t   = (unsigned short*)alloc(256 * 128 * 2);
    unsigned short* W2t   = (unsigned short*)alloc(256 * 256 * 2);
    unsigned short* W3t   = (unsigned short*)alloc(256 * 256 * 2);
    unsigned short* in_wb = (unsigned short*)alloc(768 * 256 * 2);
    unsigned short* outwb = (unsigned short*)alloc(256 * 256 * 2);
    unsigned short* wcatb = (unsigned short*)alloc(256 * 256 * 2);
    float* bcat  = (float*)alloc(256 * 4);
    unsigned short* xb    = (unsigned short*)alloc((size_t)NNODE * DIN * 2);
    float* bufA  = (float*)alloc((size_t)NNODE * HDIM * 4);             // heads th
    unsigned short* bufAb = (unsigned short*)alloc((size_t)NNODE * HDIM * 2); // conv hW
    unsigned short* aggb1 = (unsigned short*)alloc((size_t)NNODE * HDIM * 2);
    unsigned short* aggb2 = (unsigned short*)alloc((size_t)NNODE * HDIM * 2);
    float* hf    = (float*)alloc((size_t)NNODE * HDIM * 4);             // h fp32 residual
    unsigned short* hb    = (unsigned short*)alloc((size_t)NNODE * HDIM * 2);
    unsigned short* qh    = (unsigned short*)alloc((size_t)HEADS * NNODE * 32 * 2);
    unsigned short* kh    = (unsigned short*)alloc((size_t)HEADS * NNODE * 32 * 2);
    unsigned short* vh    = (unsigned short*)alloc((size_t)HEADS * NNODE * 32 * 2);
    unsigned short* po    = (unsigned short*)alloc((size_t)HEADS * NNODE * SPLIT * 32 * 2);
    float* pm    = (float*)alloc((size_t)HEADS * NNODE * SPLIT * 4);
    float* pl    = (float*)alloc((size_t)HEADS * NNODE * SPLIT * 4);
    unsigned short* ob    = (unsigned short*)alloc((size_t)NNODE * HDIM * 2);
    unsigned short* hfinb = (unsigned short*)alloc((size_t)NNODE * HDIM * 2);

    // CSR build + norms + weight/x prep
    hipMemsetAsync(degi, 0, NNODE * sizeof(int), stream);
    k_deg<<<(E + 255) / 256, 256, 0, stream>>>(ei, degi, E);
    k_scan_norm<<<1, 256, 0, stream>>>(degi, off, cursor, dinv, invdeg);
    k_fill<<<(E + 255) / 256, 256, 0, stream>>>(ei, cursor, csr, E);
    k_prep<<<2176, 256, 0, stream>>>(W1, W2, W3, in_w, outw, fp1w, pd1w, fp1b, pd1b, x,
                                     W1t, W2t, W3t, in_wb, outwb, wcatb, bcat, xb);

    dim3 g256(HDIM / 32, NNODE / 64);   // (8,64)
    dim3 g768(768 / 32, NNODE / 64);    // (24,64)

    // conv1
    k_bgemm<DIN, 1, false, false><<<g256, 256, 0, stream>>>(xb, W1t, nullptr, nullptr, bufAb, nullptr, nullptr, HDIM);
    k_gather<0><<<NNODE, 256, 0, stream>>>(bufAb, csr, off, degi, dinv, invdeg, b1, nullptr, aggb1);
    // conv2
    k_bgemm<HDIM, 1, false, false><<<g256, 256, 0, stream>>>(aggb1, W2t, nullptr, nullptr, bufAb, nullptr, nullptr, HDIM);
    k_gather<0><<<NNODE, 256, 0, stream>>>(bufAb, csr, off, degi, dinv, invdeg, b2, nullptr, aggb2);
    // conv3
    k_bgemm<HDIM, 1, false, false><<<g256, 256, 0, stream>>>(aggb2, W3t, nullptr, nullptr, bufAb, nullptr, nullptr, HDIM);
    k_gather<1><<<NNODE, 256, 0, stream>>>(bufAb, csr, off, degi, dinv, invdeg, b3, hf, hb);

    // MHA: qkv GEMM writes head-major bf16 q/k/v (q pre-scaled, log2 domain)
    k_bgemm<HDIM, 2, true, false><<<g768, 256, 0, stream>>>(hb, in_wb, in_b, nullptr, qh, kh, vh, 768);
    k_attn_mfma<<<dim3(HEADS, NNODE / 64, SPLIT), 256, 0, stream>>>(qh, kh, vh, po, pm, pl);
    k_attn_merge<<<(NNODE * HDIM) / 256, 256, 0, stream>>>(po, pm, pl, ob);
    // out-proj + residual -> bf16 h_final
    k_bgemm<HDIM, 1, true, true><<<g256, 256, 0, stream>>>(ob, outwb, outb, hf, hfinb, nullptr, nullptr, HDIM);

    // MLP heads: layer 1 as GEMM (fp32 out), layer 2 epilogue
    k_bgemm<HDIM, 0, true, false><<<g256, 256, 0, stream>>>(hfinb, wcatb, bcat, nullptr, bufA, nullptr, nullptr, HDIM);
    k_heads2<<<NNODE / 4, 256, 0, stream>>>(bufA, fp2w, fp2b, pd2w, pd2b, out);
}